// Round 1
// baseline (2048.078 us; speedup 1.0000x reference)
//
#include <hip/hip_runtime.h>
#include <math.h>

// Problem constants
constexpr int CB = 4, CN = 1024, CT = 3, CR = 4, CH = 8, CDK = 32, COUT = 256;

// ---------------------------------------------------------------------------
// zero row_sum accumulator (ws is poisoned 0xAA before every timed call)
__global__ void zero_rs(float* __restrict__ rs) {
    rs[blockIdx.x * 256 + threadIdx.x] = 0.f;
}

// ---------------------------------------------------------------------------
// Generic [1024,256] x [256,256] + bias GEMM, 64x64 tile per block, 4x4/thread.
// mode 0: z in [0,36): QKV projections. mode 1: z in [0,12): Wa head.
__global__ __launch_bounds__(256) void gemm_kernel(
    int mode,
    const float* __restrict__ X,
    const float* __restrict__ W0, const float* __restrict__ W1, const float* __restrict__ W2,
    const float* __restrict__ b0, const float* __restrict__ b1, const float* __restrict__ b2,
    float* __restrict__ Y0, float* __restrict__ Y1, float* __restrict__ Y2)
{
    int z = blockIdx.z;
    int b, t, w3;
    if (mode == 0) { b = z / 9; int r9 = z % 9; w3 = r9 / 3; t = r9 % 3; }
    else           { b = z / CT; t = z % CT; w3 = 0; }
    const float* Xb = X + (size_t)b * CN * COUT;
    const float* W  = (w3 == 0 ? W0 : (w3 == 1 ? W1 : W2)) + (size_t)t * COUT * COUT;
    const float* bs = (w3 == 0 ? b0 : (w3 == 1 ? b1 : b2)) + t * COUT;
    float* Y = (w3 == 0 ? Y0 : (w3 == 1 ? Y1 : Y2)) + ((size_t)b * CT + t) * CN * COUT;

    int row0 = blockIdx.x * 64, col0 = blockIdx.y * 64;
    __shared__ float As[16][65];
    __shared__ float Bsh[16][64];
    int tid = threadIdx.x;
    int tx = tid & 15, ty = tid >> 4;
    float acc[4][4] = {};

    for (int kt = 0; kt < COUT; kt += 16) {
        {
            int m = tid >> 2, k4 = (tid & 3) * 4;
            float4 xv = *(const float4*)(Xb + (size_t)(row0 + m) * COUT + kt + k4);
            As[k4 + 0][m] = xv.x; As[k4 + 1][m] = xv.y;
            As[k4 + 2][m] = xv.z; As[k4 + 3][m] = xv.w;
            int kk = tid >> 4, n4 = (tid & 15) * 4;
            *(float4*)(&Bsh[kk][n4]) = *(const float4*)(W + (size_t)(kt + kk) * COUT + col0 + n4);
        }
        __syncthreads();
        #pragma unroll
        for (int kk = 0; kk < 16; ++kk) {
            float a0 = As[kk][ty * 4 + 0], a1 = As[kk][ty * 4 + 1];
            float a2 = As[kk][ty * 4 + 2], a3 = As[kk][ty * 4 + 3];
            float4 bv = *(const float4*)(&Bsh[kk][tx * 4]);
            acc[0][0] += a0 * bv.x; acc[0][1] += a0 * bv.y; acc[0][2] += a0 * bv.z; acc[0][3] += a0 * bv.w;
            acc[1][0] += a1 * bv.x; acc[1][1] += a1 * bv.y; acc[1][2] += a1 * bv.z; acc[1][3] += a1 * bv.w;
            acc[2][0] += a2 * bv.x; acc[2][1] += a2 * bv.y; acc[2][2] += a2 * bv.z; acc[2][3] += a2 * bv.w;
            acc[3][0] += a3 * bv.x; acc[3][1] += a3 * bv.y; acc[3][2] += a3 * bv.z; acc[3][3] += a3 * bv.w;
        }
        __syncthreads();
    }
    float4 bb = *(const float4*)(bs + col0 + tx * 4);
    #pragma unroll
    for (int im = 0; im < 4; ++im) {
        float4 o;
        o.x = acc[im][0] + bb.x; o.y = acc[im][1] + bb.y;
        o.z = acc[im][2] + bb.z; o.w = acc[im][3] + bb.w;
        *(float4*)(Y + (size_t)(row0 + ty * 4 + im) * COUT + col0 + tx * 4) = o;
    }
}

// ---------------------------------------------------------------------------
// Qbar[b,i,:] = sum_t types[b,i,t] * Qt[b,t,i,:]
__global__ void mix_qbar(const float* __restrict__ Qt, const float* __restrict__ types,
                         float* __restrict__ Qbar)
{
    int idx = blockIdx.x * 256 + threadIdx.x;   // over B*N*64 float4s
    int bi = idx >> 6;
    int o4 = (idx & 63) * 4;
    int b = bi >> 10;
    const float* tp = types + (size_t)bi * CT;
    float t0 = tp[0], t1 = tp[1], t2 = tp[2];
    size_t nbase = ((size_t)b * CT) * CN * COUT + (size_t)(bi & 1023) * COUT + o4;
    float4 q0 = *(const float4*)(Qt + nbase);
    float4 q1 = *(const float4*)(Qt + nbase + (size_t)CN * COUT);
    float4 q2 = *(const float4*)(Qt + nbase + 2 * (size_t)CN * COUT);
    float4 o;
    o.x = t0 * q0.x + t1 * q1.x + t2 * q2.x;
    o.y = t0 * q0.y + t1 * q1.y + t2 * q2.y;
    o.z = t0 * q0.z + t1 * q1.z + t2 * q2.z;
    o.w = t0 * q0.w + t1 * q1.w + t2 * q2.w;
    *(float4*)(Qbar + (size_t)bi * COUT + o4) = o;
}

// ---------------------------------------------------------------------------
// Qr[b,r,i,h,d] = sum_e rel_att[r,h,d,e] * Qbar[b,i,h*32+e]
__global__ __launch_bounds__(256) void qr_kernel(const float* __restrict__ Qbar,
                                                 const float* __restrict__ rel_att,
                                                 float* __restrict__ Qr)
{
    int i0 = blockIdx.x * 8;
    int rh = blockIdx.y; int r = rh >> 3, h = rh & 7;
    int b = blockIdx.z;
    __shared__ float A_s[32][33];
    __shared__ float q_s[8][32];
    int tid = threadIdx.x;
    {
        int f = tid * 4; int d = f >> 5, e = f & 31;
        float4 v = *(const float4*)(rel_att + ((size_t)rh * 32 + d) * 32 + e);
        A_s[d][e] = v.x; A_s[d][e + 1] = v.y; A_s[d][e + 2] = v.z; A_s[d][e + 3] = v.w;
        int ii = tid >> 5, ee = tid & 31;
        q_s[ii][ee] = Qbar[((size_t)b * CN + i0 + ii) * COUT + h * CDK + ee];
    }
    __syncthreads();
    int d = tid & 31, ii = tid >> 5;
    float acc = 0.f;
    #pragma unroll 8
    for (int e = 0; e < 32; ++e) acc += A_s[d][e] * q_s[ii][e];
    Qr[(((size_t)b * CR + r) * CN + i0 + ii) * COUT + h * CDK + d] = acc;
}

// ---------------------------------------------------------------------------
// Vsr[b,s,r,j,h,e] = sum_d Vt[b,s,j,h,d] * rel_msg[r,h,d,e]
__global__ __launch_bounds__(256) void vsr_kernel(const float* __restrict__ Vt,
                                                  const float* __restrict__ rel_msg,
                                                  float* __restrict__ Vsr)
{
    int j0 = blockIdx.x * 8;
    int rh = blockIdx.y; int r = rh >> 3, h = rh & 7;
    int bt = blockIdx.z; int b = bt / CT, s = bt % CT;
    __shared__ float M_s[32][32];
    __shared__ float v_s[8][32];
    int tid = threadIdx.x;
    {
        int f = tid * 4; int d = f >> 5, e = f & 31;
        *(float4*)(&M_s[d][e]) = *(const float4*)(rel_msg + ((size_t)rh * 32 + d) * 32 + e);
        int jj = tid >> 5, dd = tid & 31;
        v_s[jj][dd] = Vt[(((size_t)b * CT + s) * CN + j0 + jj) * COUT + h * CDK + dd];
    }
    __syncthreads();
    int e = tid & 31, jj = tid >> 5;
    float acc = 0.f;
    #pragma unroll 8
    for (int d = 0; d < 32; ++d) acc += v_s[jj][d] * M_s[d][e];
    Vsr[((((size_t)b * CT + s) * CR + r) * CN + j0 + jj) * COUT + h * CDK + e] = acc;
}

// ---------------------------------------------------------------------------
// Fused attention: one block per (b, h, 32-row i-tile). Online softmax over j.
// Thread layout phase A (logits): jl = tid&31 (source j), g = tid>>5, rows i = g*4+k.
// Thread layout phase B (acc):    e  = tid&31 (value dim), same row group.
__global__ __launch_bounds__(256) void attn_kernel(
    const float* __restrict__ Qr,   // [B][R][N][H][DK]
    const float* __restrict__ Kt,   // [B][T][N][H][DK]
    const float* __restrict__ Vsr,  // [B][T][R][N][H][DK]
    const float* __restrict__ adj,  // [B][N][N]
    const float* __restrict__ erel, // [B][N][N][R]
    const float* __restrict__ types,// [B][N][T]
    const float* __restrict__ rel_pri, // [R][H]
    float* __restrict__ agg,        // [B][N][OUT]
    float* __restrict__ row_sum)    // [B][N]
{
    const int i0 = blockIdx.x * 32;
    const int h  = blockIdx.y;
    const int b  = blockIdx.z;
    const int tid = threadIdx.x;
    const int jl = tid & 31;
    const int g  = tid >> 5;

    __shared__ float Qr_s[CR][32][33];
    __shared__ float Kt_s[CT][32][33];
    __shared__ float W_s[CT][32][33];
    __shared__ float V_s[CT][32][32];
    __shared__ float types_s[32][4];
    __shared__ float m_s[32], l_s[32], alpha_s[32], rs_s[32];

    const float inv_sqrt = 0.17677669529663687f;  // 1/sqrt(32)
    float pri_h[CR];
    #pragma unroll
    for (int r = 0; r < CR; ++r) pri_h[r] = rel_pri[r * CH + h] * inv_sqrt;

    // stage Qr tile (4*32*32 floats = 1024 float4)
    #pragma unroll
    for (int q = 0; q < 4; ++q) {
        int f4 = q * 256 + tid;
        int r = f4 >> 8;
        int i = (f4 >> 3) & 31;
        int d = (f4 & 7) * 4;
        float4 v = *(const float4*)(Qr + (((size_t)b * CR + r) * CN + i0 + i) * COUT + h * CDK + d);
        Qr_s[r][i][d] = v.x; Qr_s[r][i][d + 1] = v.y;
        Qr_s[r][i][d + 2] = v.z; Qr_s[r][i][d + 3] = v.w;
    }
    if (tid < 32) { m_s[tid] = -3.0e38f; l_s[tid] = 0.f; rs_s[tid] = 0.f; }

    float acc[4] = {0.f, 0.f, 0.f, 0.f};

    for (int j0 = 0; j0 < CN; j0 += 32) {
        __syncthreads();   // previous iteration's readers done before restaging
        // stage Kt tile (3*32*32 floats = 768 float4)
        #pragma unroll
        for (int q = 0; q < 3; ++q) {
            int f4 = q * 256 + tid;
            int s = f4 >> 8;
            int j = (f4 >> 3) & 31;
            int d = (f4 & 7) * 4;
            float4 v = *(const float4*)(Kt + (((size_t)b * CT + s) * CN + j0 + j) * COUT + h * CDK + d);
            Kt_s[s][j][d] = v.x; Kt_s[s][j][d + 1] = v.y;
            Kt_s[s][j][d + 2] = v.z; Kt_s[s][j][d + 3] = v.w;
        }
        if (tid < 32) {
            const float* tp = types + ((size_t)b * CN + j0 + tid) * CT;
            types_s[tid][0] = tp[0]; types_s[tid][1] = tp[1]; types_s[tid][2] = tp[2];
        }
        __syncthreads();

        // D[k][s*4+r] = dot(Qr[r, i=g*4+k, h], Kt[s, j0+jl, h])
        float D[4][12];
        #pragma unroll
        for (int k = 0; k < 4; ++k)
            #pragma unroll
            for (int q = 0; q < 12; ++q) D[k][q] = 0.f;
        #pragma unroll 4
        for (int d = 0; d < 32; ++d) {
            float kt0 = Kt_s[0][jl][d], kt1 = Kt_s[1][jl][d], kt2 = Kt_s[2][jl][d];
            #pragma unroll
            for (int k = 0; k < 4; ++k) {
                #pragma unroll
                for (int r = 0; r < 4; ++r) {
                    float qv = Qr_s[r][g * 4 + k][d];
                    D[k][r]     += qv * kt0;
                    D[k][4 + r] += qv * kt1;
                    D[k][8 + r] += qv * kt2;
                }
            }
        }
        float ty0 = types_s[jl][0], ty1 = types_s[jl][1], ty2 = types_s[jl][2];

        // logits
        float cr[4][4], L[4];
        #pragma unroll
        for (int k = 0; k < 4; ++k) {
            int i = g * 4 + k;
            float a = adj[((size_t)b * CN + i0 + i) * CN + j0 + jl];
            float4 er = *(const float4*)(erel + (((size_t)b * CN + i0 + i) * CN + j0 + jl) * CR);
            cr[k][0] = a * er.x * pri_h[0]; cr[k][1] = a * er.y * pri_h[1];
            cr[k][2] = a * er.z * pri_h[2]; cr[k][3] = a * er.w * pri_h[3];
            L[k] = cr[k][0] * (ty0 * D[k][0] + ty1 * D[k][4] + ty2 * D[k][8])
                 + cr[k][1] * (ty0 * D[k][1] + ty1 * D[k][5] + ty2 * D[k][9])
                 + cr[k][2] * (ty0 * D[k][2] + ty1 * D[k][6] + ty2 * D[k][10])
                 + cr[k][3] * (ty0 * D[k][3] + ty1 * D[k][7] + ty2 * D[k][11]);
        }

        // per-row reductions over the 32 j-lanes, online softmax update
        float P[4], mnew[4], psum[4], lsum[4], mold[4];
        #pragma unroll
        for (int k = 0; k < 4; ++k) {
            float mx = L[k], sm = L[k];
            #pragma unroll
            for (int mk = 16; mk >= 1; mk >>= 1) {
                mx = fmaxf(mx, __shfl_xor(mx, mk, 32));
                sm = sm + __shfl_xor(sm, mk, 32);
            }
            mold[k] = m_s[g * 4 + k];                 // read-before-write, same wave
            float mn = fmaxf(mold[k], mx);
            mnew[k] = mn;
            P[k] = __expf(L[k] - mn);
            float ps = P[k];
            #pragma unroll
            for (int mk = 16; mk >= 1; mk >>= 1) ps += __shfl_xor(ps, mk, 32);
            psum[k] = ps; lsum[k] = sm;
        }
        if (jl == 0) {
            #pragma unroll
            for (int k = 0; k < 4; ++k) {
                int i = g * 4 + k;
                float al = __expf(mold[k] - mnew[k]);
                m_s[i] = mnew[k];
                alpha_s[i] = al;
                l_s[i] = l_s[i] * al + psum[k];
                rs_s[i] += lsum[k];
            }
        }
        #pragma unroll
        for (int k = 0; k < 4; ++k) acc[k] *= alpha_s[g * 4 + k];  // same-wave visibility

        // value accumulation per relation
        #pragma unroll 1
        for (int r = 0; r < 4; ++r) {
            __syncthreads();   // previous r's readers done
            #pragma unroll
            for (int q = 0; q < 3; ++q) {
                int f4 = q * 256 + tid;
                int s = f4 >> 8;
                int j = (f4 >> 3) & 31;
                int e = (f4 & 7) * 4;
                *(float4*)(&V_s[s][j][e]) =
                    *(const float4*)(Vsr + ((((size_t)b * CT + s) * CR + r) * CN + j0 + j) * COUT + h * CDK + e);
            }
            #pragma unroll
            for (int k = 0; k < 4; ++k) {
                int i = g * 4 + k;
                float pc = P[k] * cr[k][r];
                W_s[0][i][jl] = pc * ty0 * D[k][r];
                W_s[1][i][jl] = pc * ty1 * D[k][4 + r];
                W_s[2][i][jl] = pc * ty2 * D[k][8 + r];
            }
            __syncthreads();
            #pragma unroll 1
            for (int s = 0; s < 3; ++s) {
                #pragma unroll 8
                for (int j = 0; j < 32; ++j) {
                    float v = V_s[s][j][jl];
                    acc[0] += W_s[s][g * 4 + 0][j] * v;
                    acc[1] += W_s[s][g * 4 + 1][j] * v;
                    acc[2] += W_s[s][g * 4 + 2][j] * v;
                    acc[3] += W_s[s][g * 4 + 3][j] * v;
                }
            }
        }
    }
    __syncthreads();
    #pragma unroll
    for (int k = 0; k < 4; ++k) {
        float li = l_s[g * 4 + k];
        agg[((size_t)b * CN + i0 + g * 4 + k) * COUT + h * CDK + jl] = acc[k] / li;
    }
    if (tid < 32) atomicAdd(&row_sum[b * CN + i0 + tid], rs_s[tid]);
}

// ---------------------------------------------------------------------------
// gate by row_sum, exact gelu
__global__ void gelu_gate(const float* __restrict__ agg, const float* __restrict__ row_sum,
                          float* __restrict__ gout)
{
    int idx = blockIdx.x * 256 + threadIdx.x;   // over B*N*64 float4s
    int bi = idx >> 6;
    float rs = row_sum[bi];
    float4 v = *(const float4*)(agg + (size_t)idx * 4);
    if (!(rs > 1e-6f)) { v.x = 0.f; v.y = 0.f; v.z = 0.f; v.w = 0.f; }
    const float is2 = 0.70710678118654752f;
    float4 o;
    o.x = 0.5f * v.x * (1.f + erff(v.x * is2));
    o.y = 0.5f * v.y * (1.f + erff(v.y * is2));
    o.z = 0.5f * v.z * (1.f + erff(v.z * is2));
    o.w = 0.5f * v.w * (1.f + erff(v.w * is2));
    *(float4*)(gout + (size_t)idx * 4) = o;
}

// ---------------------------------------------------------------------------
// gated residual + layernorm + soft-type mix. One block per (b,i) row.
__global__ __launch_bounds__(256) void final_ln(
    const float* __restrict__ trans, const float* __restrict__ x,
    const float* __restrict__ types, const float* __restrict__ skip,
    const float* __restrict__ gamma, const float* __restrict__ beta,
    float* __restrict__ out)
{
    int bi = blockIdx.x;
    int b = bi >> 10;
    int i = bi & 1023;
    int o = threadIdx.x;
    __shared__ float red[4];
    float xo = x[(size_t)bi * COUT + o];
    float accum = 0.f;
    #pragma unroll 1
    for (int t = 0; t < CT; ++t) {
        float al = 1.f / (1.f + __expf(-skip[t]));
        float tr = trans[(((size_t)b * CT + t) * CN + i) * COUT + o];
        float res = tr * al + xo * (1.f - al);
        float v = res;
        #pragma unroll
        for (int mk = 1; mk < 64; mk <<= 1) v += __shfl_xor(v, mk);
        __syncthreads();
        if ((o & 63) == 0) red[o >> 6] = v;
        __syncthreads();
        float mu = (red[0] + red[1] + red[2] + red[3]) * (1.f / COUT);
        float dc = res - mu;
        float v2 = dc * dc;
        #pragma unroll
        for (int mk = 1; mk < 64; mk <<= 1) v2 += __shfl_xor(v2, mk);
        __syncthreads();
        if ((o & 63) == 0) red[o >> 6] = v2;
        __syncthreads();
        float var = (red[0] + red[1] + red[2] + red[3]) * (1.f / COUT);
        float ln = dc * rsqrtf(var + 1e-5f) * gamma[t * COUT + o] + beta[t * COUT + o];
        accum += types[(size_t)bi * CT + t] * ln;
    }
    out[(size_t)bi * COUT + o] = accum;
}

// ---------------------------------------------------------------------------
extern "C" void kernel_launch(void* const* d_in, const int* in_sizes, int n_in,
                              void* d_out, int out_size, void* d_ws, size_t ws_size,
                              hipStream_t stream)
{
    (void)in_sizes; (void)n_in; (void)out_size; (void)ws_size;
    const float* nf      = (const float*)d_in[0];
    const float* types   = (const float*)d_in[1];
    const float* adj     = (const float*)d_in[2];
    const float* erel    = (const float*)d_in[3];
    const float* Wq      = (const float*)d_in[4];
    const float* bq      = (const float*)d_in[5];
    const float* Wk      = (const float*)d_in[6];
    const float* bk      = (const float*)d_in[7];
    const float* Wv      = (const float*)d_in[8];
    const float* bv      = (const float*)d_in[9];
    const float* Wa      = (const float*)d_in[10];
    const float* ba      = (const float*)d_in[11];
    const float* rel_pri = (const float*)d_in[12];
    const float* rel_att = (const float*)d_in[13];
    const float* rel_msg = (const float*)d_in[14];
    const float* skip    = (const float*)d_in[15];
    const float* gamma   = (const float*)d_in[16];
    const float* beta    = (const float*)d_in[17];
    float* out = (float*)d_out;

    float* ws = (float*)d_ws;
    size_t o = 0;
    float* Qt   = ws + o; o += (size_t)CB * CT * CN * COUT;   // 3.15M
    float* Ktb  = ws + o; o += (size_t)CB * CT * CN * COUT;
    float* Vtb  = ws + o; o += (size_t)CB * CT * CN * COUT;
    float* Qbar = ws + o; o += (size_t)CB * CN * COUT;
    float* Qrb  = ws + o; o += (size_t)CB * CR * CN * COUT;
    float* Vsrb = ws + o; o += (size_t)CB * CT * CR * CN * COUT;
    float* aggb = ws + o; o += (size_t)CB * CN * COUT;
    float* rsb  = ws + o; o += (size_t)CB * CN;
    float* gbuf   = Qt;    // Qt dead after mix_qbar
    float* transb = Vtb;   // Vt dead after vsr_kernel

    zero_rs<<<CB * CN / 256, 256, 0, stream>>>(rsb);
    gemm_kernel<<<dim3(16, 4, CB * 9), 256, 0, stream>>>(0, nf, Wq, Wk, Wv, bq, bk, bv, Qt, Ktb, Vtb);
    mix_qbar<<<CB * CN * COUT / 4 / 256, 256, 0, stream>>>(Qt, types, Qbar);
    qr_kernel<<<dim3(CN / 8, CR * CH, CB), 256, 0, stream>>>(Qbar, rel_att, Qrb);
    vsr_kernel<<<dim3(CN / 8, CR * CH, CB * CT), 256, 0, stream>>>(Vtb, rel_msg, Vsrb);
    attn_kernel<<<dim3(CN / 32, CH, CB), 256, 0, stream>>>(Qrb, Ktb, Vsrb, adj, erel, types,
                                                           rel_pri, aggb, rsb);
    gelu_gate<<<CB * CN * COUT / 4 / 256, 256, 0, stream>>>(aggb, rsb, gbuf);
    gemm_kernel<<<dim3(16, 4, CB * CT), 256, 0, stream>>>(1, gbuf, Wa, Wa, Wa, ba, ba, ba,
                                                          transb, transb, transb);
    final_ln<<<CB * CN, 256, 0, stream>>>(transb, nf, types, skip, gamma, beta, out);
}

// Round 2
// 516.633 us; speedup vs baseline: 3.9643x; 3.9643x over previous
//
#include <hip/hip_runtime.h>
#include <math.h>

// Problem constants
constexpr int CB = 4, CN = 1024, CT = 3, CR = 4, CH = 8, CDK = 32, COUT = 256;

typedef __attribute__((ext_vector_type(4))) float f32x4;
typedef __attribute__((ext_vector_type(8))) short s16x8;
typedef __attribute__((ext_vector_type(4))) _Float16 f16x4;
typedef __attribute__((ext_vector_type(8))) _Float16 f16x8;
typedef __attribute__((ext_vector_type(4))) unsigned short u16x4;

__device__ inline unsigned short f2bf(float x) {
    unsigned u = __float_as_uint(x);
    unsigned r = (u + 0x7fffu + ((u >> 16) & 1u)) >> 16;
    return (unsigned short)r;
}
__device__ inline float bf2f(unsigned short b) {
    return __uint_as_float(((unsigned)b) << 16);
}

// ---------------------------------------------------------------------------
__global__ void zero_rs(float* __restrict__ rs) {
    rs[blockIdx.x * 256 + threadIdx.x] = 0.f;
}

// ---------------------------------------------------------------------------
// Generic [1024,256] x [256,256] + bias GEMM, 64x64 tile per block, 4x4/thread.
__global__ __launch_bounds__(256) void gemm_kernel(
    int mode,
    const float* __restrict__ X,
    const float* __restrict__ W0, const float* __restrict__ W1, const float* __restrict__ W2,
    const float* __restrict__ b0, const float* __restrict__ b1, const float* __restrict__ b2,
    float* __restrict__ Y0, float* __restrict__ Y1, float* __restrict__ Y2)
{
    int z = blockIdx.z;
    int b, t, w3;
    if (mode == 0) { b = z / 9; int r9 = z % 9; w3 = r9 / 3; t = r9 % 3; }
    else           { b = z / CT; t = z % CT; w3 = 0; }
    const float* Xb = X + (size_t)b * CN * COUT;
    const float* W  = (w3 == 0 ? W0 : (w3 == 1 ? W1 : W2)) + (size_t)t * COUT * COUT;
    const float* bs = (w3 == 0 ? b0 : (w3 == 1 ? b1 : b2)) + t * COUT;
    float* Y = (w3 == 0 ? Y0 : (w3 == 1 ? Y1 : Y2)) + ((size_t)b * CT + t) * CN * COUT;

    int row0 = blockIdx.x * 64, col0 = blockIdx.y * 64;
    __shared__ float As[16][65];
    __shared__ float Bsh[16][64];
    int tid = threadIdx.x;
    int tx = tid & 15, ty = tid >> 4;
    float acc[4][4] = {};

    for (int kt = 0; kt < COUT; kt += 16) {
        {
            int m = tid >> 2, k4 = (tid & 3) * 4;
            float4 xv = *(const float4*)(Xb + (size_t)(row0 + m) * COUT + kt + k4);
            As[k4 + 0][m] = xv.x; As[k4 + 1][m] = xv.y;
            As[k4 + 2][m] = xv.z; As[k4 + 3][m] = xv.w;
            int kk = tid >> 4, n4 = (tid & 15) * 4;
            *(float4*)(&Bsh[kk][n4]) = *(const float4*)(W + (size_t)(kt + kk) * COUT + col0 + n4);
        }
        __syncthreads();
        #pragma unroll
        for (int kk = 0; kk < 16; ++kk) {
            float a0 = As[kk][ty * 4 + 0], a1 = As[kk][ty * 4 + 1];
            float a2 = As[kk][ty * 4 + 2], a3 = As[kk][ty * 4 + 3];
            float4 bv = *(const float4*)(&Bsh[kk][tx * 4]);
            acc[0][0] += a0 * bv.x; acc[0][1] += a0 * bv.y; acc[0][2] += a0 * bv.z; acc[0][3] += a0 * bv.w;
            acc[1][0] += a1 * bv.x; acc[1][1] += a1 * bv.y; acc[1][2] += a1 * bv.z; acc[1][3] += a1 * bv.w;
            acc[2][0] += a2 * bv.x; acc[2][1] += a2 * bv.y; acc[2][2] += a2 * bv.z; acc[2][3] += a2 * bv.w;
            acc[3][0] += a3 * bv.x; acc[3][1] += a3 * bv.y; acc[3][2] += a3 * bv.z; acc[3][3] += a3 * bv.w;
        }
        __syncthreads();
    }
    float4 bb = *(const float4*)(bs + col0 + tx * 4);
    #pragma unroll
    for (int im = 0; im < 4; ++im) {
        float4 o;
        o.x = acc[im][0] + bb.x; o.y = acc[im][1] + bb.y;
        o.z = acc[im][2] + bb.z; o.w = acc[im][3] + bb.w;
        *(float4*)(Y + (size_t)(row0 + ty * 4 + im) * COUT + col0 + tx * 4) = o;
    }
}

// ---------------------------------------------------------------------------
// Qbar[b,i,:] = sum_t types[b,i,t] * Qt[b,t,i,:]
__global__ void mix_qbar(const float* __restrict__ Qt, const float* __restrict__ types,
                         float* __restrict__ Qbar)
{
    int idx = blockIdx.x * 256 + threadIdx.x;
    int bi = idx >> 6;
    int o4 = (idx & 63) * 4;
    int b = bi >> 10;
    const float* tp = types + (size_t)bi * CT;
    float t0 = tp[0], t1 = tp[1], t2 = tp[2];
    size_t nbase = ((size_t)b * CT) * CN * COUT + (size_t)(bi & 1023) * COUT + o4;
    float4 q0 = *(const float4*)(Qt + nbase);
    float4 q1 = *(const float4*)(Qt + nbase + (size_t)CN * COUT);
    float4 q2 = *(const float4*)(Qt + nbase + 2 * (size_t)CN * COUT);
    float4 o;
    o.x = t0 * q0.x + t1 * q1.x + t2 * q2.x;
    o.y = t0 * q0.y + t1 * q1.y + t2 * q2.y;
    o.z = t0 * q0.z + t1 * q1.z + t2 * q2.z;
    o.w = t0 * q0.w + t1 * q1.w + t2 * q2.w;
    *(float4*)(Qbar + (size_t)bi * COUT + o4) = o;
}

// ---------------------------------------------------------------------------
// Qr[b,r,i,h,d] = (pri[r,h]/sqrt(dk)) * sum_e rel_att[r,h,d,e]*Qbar[b,i,h*32+e]
// output split into bf16 hi/lo pair.
__global__ __launch_bounds__(256) void qr2_kernel(const float* __restrict__ Qbar,
                                                  const float* __restrict__ rel_att,
                                                  const float* __restrict__ rel_pri,
                                                  unsigned short* __restrict__ Qrhi,
                                                  unsigned short* __restrict__ Qrlo)
{
    int i0 = blockIdx.x * 8;
    int rh = blockIdx.y; int r = rh >> 3, h = rh & 7;
    int b = blockIdx.z;
    __shared__ float A_s[32][33];
    __shared__ float q_s[8][32];
    int tid = threadIdx.x;
    {
        int f = tid * 4; int d = f >> 5, e = f & 31;
        float4 v = *(const float4*)(rel_att + ((size_t)rh * 32 + d) * 32 + e);
        A_s[d][e] = v.x; A_s[d][e + 1] = v.y; A_s[d][e + 2] = v.z; A_s[d][e + 3] = v.w;
        int ii = tid >> 5, ee = tid & 31;
        q_s[ii][ee] = Qbar[((size_t)b * CN + i0 + ii) * COUT + h * CDK + ee];
    }
    __syncthreads();
    int d = tid & 31, ii = tid >> 5;
    float acc = 0.f;
    #pragma unroll 8
    for (int e = 0; e < 32; ++e) acc += A_s[d][e] * q_s[ii][e];
    const float inv_sqrt = 0.17677669529663687f;
    float v = acc * rel_pri[rh] * inv_sqrt;
    unsigned short hb = f2bf(v);
    float lo = v - bf2f(hb);
    size_t oidx = (((size_t)b * CR + r) * CN + i0 + ii) * COUT + h * CDK + d;
    Qrhi[oidx] = hb;
    Qrlo[oidx] = f2bf(lo);
}

// ---------------------------------------------------------------------------
// Kt fp32 -> bf16 hi/lo split (same layout)
__global__ void split_kt(const float* __restrict__ Kt,
                         unsigned short* __restrict__ hi, unsigned short* __restrict__ lo)
{
    size_t idx = ((size_t)blockIdx.x * 256 + threadIdx.x) * 4;
    f32x4 v = *(const f32x4*)(Kt + idx);
    u16x4 hv, lv;
    #pragma unroll
    for (int k = 0; k < 4; ++k) {
        unsigned short hb = f2bf(v[k]);
        hv[k] = hb;
        lv[k] = f2bf(v[k] - bf2f(hb));
    }
    *(u16x4*)(hi + idx) = hv;
    *(u16x4*)(lo + idx) = lv;
}

// ---------------------------------------------------------------------------
// VtyT[b,s,h,e,j] = types[b,j,s] * Vt[b,s,j,h*32+e]  (f16, j contiguous)
__global__ __launch_bounds__(256) void vtyT_kernel(const float* __restrict__ Vt,
                                                   const float* __restrict__ types,
                                                   _Float16* __restrict__ VtyT)
{
    int j0 = blockIdx.x * 64; int h = blockIdx.y; int bs = blockIdx.z;
    int b = bs / 3, s = bs % 3;
    __shared__ float tile[32][72];
    int t = threadIdx.x;
    int jj = t >> 2, e8 = (t & 3) * 8;
    float ty = types[((size_t)b * CN + j0 + jj) * CT + s];
    const float* src = Vt + ((size_t)bs * CN + j0 + jj) * COUT + h * CDK + e8;
    f32x4 v0 = *(const f32x4*)(src);
    f32x4 v1 = *(const f32x4*)(src + 4);
    #pragma unroll
    for (int k = 0; k < 4; ++k) { tile[e8 + k][jj] = v0[k] * ty; tile[e8 + 4 + k][jj] = v1[k] * ty; }
    __syncthreads();
    int e = t >> 3, jr = (t & 7) * 8;
    f16x8 o;
    #pragma unroll
    for (int k = 0; k < 8; ++k) o[k] = (_Float16)tile[e][jr + k];
    *(f16x8*)(VtyT + (((size_t)bs * CH + h) * CDK + e) * CN + j0 + jr) = o;
}

// ---------------------------------------------------------------------------
// MT[r,h,e,e'] = rel_msg[r,h,e',e]  (f16)
__global__ void mT_kernel(const float* __restrict__ rel_msg, _Float16* __restrict__ MT)
{
    int rh = blockIdx.x; int t = threadIdx.x;
    int e = t >> 3, ep4 = (t & 7) * 4;
    f16x4 o;
    #pragma unroll
    for (int k = 0; k < 4; ++k)
        o[k] = (_Float16)rel_msg[((size_t)rh * 32 + ep4 + k) * 32 + e];
    *(f16x4*)(MT + ((size_t)rh * 32 + e) * 32 + ep4) = o;
}

// ---------------------------------------------------------------------------
// MFMA flash attention. Block = 4 waves; wave w owns i-rows blockIdx.x*64+w*16..+15.
// Per 16-j step: D^T[j][i] per (s,r) via bf16-split mfma_16x16x32; online softmax
// over j (rows = quad*4+reg, identity with K=16 B-operand layout); P*V via
// mfma_16x16x16f16 into U_r; epilogue applies rel_msg via MFMA.
__global__ __launch_bounds__(256, 2) void attn2_kernel(
    const unsigned short* __restrict__ Qrhi, const unsigned short* __restrict__ Qrlo,
    const unsigned short* __restrict__ Kthi, const unsigned short* __restrict__ Ktlo,
    const _Float16* __restrict__ VtyT, const _Float16* __restrict__ MT,
    const float* __restrict__ adj, const float* __restrict__ erel,
    const float* __restrict__ types,
    float* __restrict__ agg, float* __restrict__ row_sum)
{
    const int h = blockIdx.y, b = blockIdx.z;
    const int wave = threadIdx.x >> 6, lane = threadIdx.x & 63;
    const int col = lane & 15, quad = lane >> 4;
    const int i = blockIdx.x * 64 + wave * 16 + col;

    // loop-invariant Qr B-frags (B[col=i][k=d])
    s16x8 qrh[4], qrl[4];
    #pragma unroll
    for (int r = 0; r < 4; ++r) {
        size_t off = (((size_t)(b * 4 + r) * CN + i) * COUT) + h * CDK + quad * 8;
        qrh[r] = *(const s16x8*)(Qrhi + off);
        qrl[r] = *(const s16x8*)(Qrlo + off);
    }

    f32x4 U[4][2];
    #pragma unroll
    for (int r = 0; r < 4; ++r) { U[r][0] = (f32x4){0.f,0.f,0.f,0.f}; U[r][1] = (f32x4){0.f,0.f,0.f,0.f}; }
    float m = -3.0e38f, l = 0.f, rs = 0.f;

    const size_t ktbase = ((size_t)(b * 3) * CN + col) * COUT + h * CDK + quad * 8;
    size_t vbase[3];
    #pragma unroll
    for (int s = 0; s < 3; ++s)
        vbase[s] = (((size_t)(b * 3 + s) * CH + h) * CDK + col) * CN + quad * 4;
    const size_t adjbase = ((size_t)b * CN + i) * CN + quad * 4;
    const size_t erbase = adjbase * 4;
    const size_t tybase = ((size_t)b * CN + quad * 4) * 3;

    #pragma unroll 1
    for (int j0 = 0; j0 < CN; j0 += 16) {
        // A-frags Kt (A[row=j][k=d])
        s16x8 kh[3], kl[3];
        #pragma unroll
        for (int s = 0; s < 3; ++s) {
            size_t off = ktbase + (size_t)s * CN * COUT + (size_t)j0 * COUT;
            kh[s] = *(const s16x8*)(Kthi + off);
            kl[s] = *(const s16x8*)(Ktlo + off);
        }
        // D^T = Kt * Qr^T with bf16 hi/lo split (3 products)
        f32x4 Dt[3][4];
        #pragma unroll
        for (int s = 0; s < 3; ++s)
            #pragma unroll
            for (int r = 0; r < 4; ++r) {
                f32x4 d = {0.f, 0.f, 0.f, 0.f};
                d = __builtin_amdgcn_mfma_f32_16x16x32_bf16(kl[s], qrh[r], d, 0, 0, 0);
                d = __builtin_amdgcn_mfma_f32_16x16x32_bf16(kh[s], qrl[r], d, 0, 0, 0);
                d = __builtin_amdgcn_mfma_f32_16x16x32_bf16(kh[s], qrh[r], d, 0, 0, 0);
                Dt[s][r] = d;
            }
        // per-lane rows j = j0 + quad*4 + reg, col i
        float ty0[4], ty1[4], ty2[4];
        #pragma unroll
        for (int reg = 0; reg < 4; ++reg) {
            const float* tp = types + tybase + (size_t)(j0 + reg) * 3;
            ty0[reg] = tp[0]; ty1[reg] = tp[1]; ty2[reg] = tp[2];
        }
        f32x4 av = *(const f32x4*)(adj + adjbase + j0);
        float L[4], apr[4][4];
        #pragma unroll
        for (int reg = 0; reg < 4; ++reg) {
            f32x4 er = *(const f32x4*)(erel + erbase + (size_t)(j0 + reg) * 4);
            float a = av[reg];
            float Lr = 0.f;
            #pragma unroll
            for (int r = 0; r < 4; ++r) {
                float ap = a * er[r];
                apr[reg][r] = ap;
                float dm = ty0[reg] * Dt[0][r][reg] + ty1[reg] * Dt[1][r][reg]
                         + ty2[reg] * Dt[2][r][reg];
                Lr += ap * dm;
            }
            L[reg] = Lr;
        }
        rs += L[0] + L[1] + L[2] + L[3];
        // online softmax over j (reduce over quads: xor 16, 32)
        float mx = fmaxf(fmaxf(L[0], L[1]), fmaxf(L[2], L[3]));
        mx = fmaxf(mx, __shfl_xor(mx, 16));
        mx = fmaxf(mx, __shfl_xor(mx, 32));
        float mnew = fmaxf(m, mx);
        float alpha = __expf(m - mnew);
        float P[4]; float ps = 0.f;
        #pragma unroll
        for (int reg = 0; reg < 4; ++reg) { P[reg] = __expf(L[reg] - mnew); ps += P[reg]; }
        ps += __shfl_xor(ps, 16);
        ps += __shfl_xor(ps, 32);
        l = l * alpha + ps;
        m = mnew;
        #pragma unroll
        for (int r = 0; r < 4; ++r) { U[r][0] *= alpha; U[r][1] *= alpha; }
        float pcr[4][4];
        #pragma unroll
        for (int reg = 0; reg < 4; ++reg)
            #pragma unroll
            for (int r = 0; r < 4; ++r) pcr[reg][r] = P[reg] * apr[reg][r];
        // P*V: W B-frag is identity with D^T C-layout (reg<->k). U^T[e][i] += Vty * W
        #pragma unroll
        for (int s = 0; s < 3; ++s) {
            f16x4 v0 = *(const f16x4*)(VtyT + vbase[s] + j0);
            f16x4 v1 = *(const f16x4*)(VtyT + vbase[s] + 16 * CN + j0);
            #pragma unroll
            for (int r = 0; r < 4; ++r) {
                f16x4 w;
                w[0] = (_Float16)(pcr[0][r] * Dt[s][r][0]);
                w[1] = (_Float16)(pcr[1][r] * Dt[s][r][1]);
                w[2] = (_Float16)(pcr[2][r] * Dt[s][r][2]);
                w[3] = (_Float16)(pcr[3][r] * Dt[s][r][3]);
                U[r][0] = __builtin_amdgcn_mfma_f32_16x16x16f16(v0, w, U[r][0], 0, 0, 0);
                U[r][1] = __builtin_amdgcn_mfma_f32_16x16x16f16(v1, w, U[r][1], 0, 0, 0);
            }
        }
    }
    // epilogue: normalize, apply rel_msg via MFMA (U^T C-layout == B-frag, k=e')
    float il = 1.f / l;
    f16x4 Uh[4][2];
    #pragma unroll
    for (int r = 0; r < 4; ++r)
        #pragma unroll
        for (int eh = 0; eh < 2; ++eh) {
            Uh[r][eh][0] = (_Float16)(U[r][eh][0] * il);
            Uh[r][eh][1] = (_Float16)(U[r][eh][1] * il);
            Uh[r][eh][2] = (_Float16)(U[r][eh][2] * il);
            Uh[r][eh][3] = (_Float16)(U[r][eh][3] * il);
        }
    #pragma unroll
    for (int eo = 0; eo < 2; ++eo) {
        f32x4 acc = {0.f, 0.f, 0.f, 0.f};
        #pragma unroll
        for (int r = 0; r < 4; ++r)
            #pragma unroll
            for (int ep = 0; ep < 2; ++ep) {
                f16x4 mt = *(const f16x4*)(MT + ((size_t)(r * 8 + h) * 32 + eo * 16 + col) * 32
                                               + ep * 16 + quad * 4);
                acc = __builtin_amdgcn_mfma_f32_16x16x16f16(mt, Uh[r][ep], acc, 0, 0, 0);
            }
        *(f32x4*)(agg + ((size_t)b * CN + i) * COUT + h * CDK + eo * 16 + quad * 4) = acc;
    }
    rs += __shfl_xor(rs, 16);
    rs += __shfl_xor(rs, 32);
    if (quad == 0) atomicAdd(row_sum + (size_t)b * CN + i, rs);
}

// ---------------------------------------------------------------------------
__global__ void gelu_gate(const float* __restrict__ agg, const float* __restrict__ row_sum,
                          float* __restrict__ gout)
{
    int idx = blockIdx.x * 256 + threadIdx.x;
    int bi = idx >> 6;
    float rsv = row_sum[bi];
    float4 v = *(const float4*)(agg + (size_t)idx * 4);
    if (!(rsv > 1e-6f)) { v.x = 0.f; v.y = 0.f; v.z = 0.f; v.w = 0.f; }
    const float is2 = 0.70710678118654752f;
    float4 o;
    o.x = 0.5f * v.x * (1.f + erff(v.x * is2));
    o.y = 0.5f * v.y * (1.f + erff(v.y * is2));
    o.z = 0.5f * v.z * (1.f + erff(v.z * is2));
    o.w = 0.5f * v.w * (1.f + erff(v.w * is2));
    *(float4*)(gout + (size_t)idx * 4) = o;
}

// ---------------------------------------------------------------------------
__global__ __launch_bounds__(256) void final_ln(
    const float* __restrict__ trans, const float* __restrict__ x,
    const float* __restrict__ types, const float* __restrict__ skip,
    const float* __restrict__ gamma, const float* __restrict__ beta,
    float* __restrict__ out)
{
    int bi = blockIdx.x;
    int b = bi >> 10;
    int i = bi & 1023;
    int o = threadIdx.x;
    __shared__ float red[4];
    float xo = x[(size_t)bi * COUT + o];
    float accum = 0.f;
    #pragma unroll 1
    for (int t = 0; t < CT; ++t) {
        float al = 1.f / (1.f + __expf(-skip[t]));
        float tr = trans[(((size_t)b * CT + t) * CN + i) * COUT + o];
        float res = tr * al + xo * (1.f - al);
        float v = res;
        #pragma unroll
        for (int mk = 1; mk < 64; mk <<= 1) v += __shfl_xor(v, mk);
        __syncthreads();
        if ((o & 63) == 0) red[o >> 6] = v;
        __syncthreads();
        float mu = (red[0] + red[1] + red[2] + red[3]) * (1.f / COUT);
        float dc = res - mu;
        float v2 = dc * dc;
        #pragma unroll
        for (int mk = 1; mk < 64; mk <<= 1) v2 += __shfl_xor(v2, mk);
        __syncthreads();
        if ((o & 63) == 0) red[o >> 6] = v2;
        __syncthreads();
        float var = (red[0] + red[1] + red[2] + red[3]) * (1.f / COUT);
        float ln = dc * rsqrtf(var + 1e-5f) * gamma[t * COUT + o] + beta[t * COUT + o];
        accum += types[(size_t)bi * CT + t] * ln;
    }
    out[(size_t)bi * COUT + o] = accum;
}

// ---------------------------------------------------------------------------
extern "C" void kernel_launch(void* const* d_in, const int* in_sizes, int n_in,
                              void* d_out, int out_size, void* d_ws, size_t ws_size,
                              hipStream_t stream)
{
    (void)in_sizes; (void)n_in; (void)out_size; (void)ws_size;
    const float* nf      = (const float*)d_in[0];
    const float* types   = (const float*)d_in[1];
    const float* adj     = (const float*)d_in[2];
    const float* erel    = (const float*)d_in[3];
    const float* Wq      = (const float*)d_in[4];
    const float* bq      = (const float*)d_in[5];
    const float* Wk      = (const float*)d_in[6];
    const float* bk      = (const float*)d_in[7];
    const float* Wv      = (const float*)d_in[8];
    const float* bv      = (const float*)d_in[9];
    const float* Wa      = (const float*)d_in[10];
    const float* ba      = (const float*)d_in[11];
    const float* rel_pri = (const float*)d_in[12];
    const float* rel_att = (const float*)d_in[13];
    const float* rel_msg = (const float*)d_in[14];
    const float* skip    = (const float*)d_in[15];
    const float* gamma   = (const float*)d_in[16];
    const float* beta    = (const float*)d_in[17];
    float* out = (float*)d_out;

    float* ws = (float*)d_ws;
    size_t o = 0;
    float* Qt   = ws + o; o += (size_t)CB * CT * CN * COUT;   // 3.146M f32
    float* Ktb  = ws + o; o += (size_t)CB * CT * CN * COUT;
    float* Vtb  = ws + o; o += (size_t)CB * CT * CN * COUT;
    float* Qbar = ws + o; o += (size_t)CB * CN * COUT;
    float* aggb = ws + o; o += (size_t)CB * CN * COUT;
    float* rsb  = ws + o; o += (size_t)CB * CN;
    unsigned short* Qrhi = (unsigned short*)(ws + o); o += (size_t)CB * CR * CN * COUT / 2;
    unsigned short* Qrlo = (unsigned short*)(ws + o); o += (size_t)CB * CR * CN * COUT / 2;
    unsigned short* Kthi = (unsigned short*)(ws + o); o += (size_t)CB * CT * CN * COUT / 2;
    unsigned short* Ktlo = (unsigned short*)(ws + o); o += (size_t)CB * CT * CN * COUT / 2;
    _Float16* VtyTb = (_Float16*)(ws + o);            o += (size_t)CB * CT * CN * COUT / 2;
    _Float16* MTb   = (_Float16*)(ws + o);            o += (size_t)CR * CH * CDK * CDK / 2;
    float* gbuf   = Qt;    // Qt dead after mix_qbar
    float* transb = Vtb;   // Vt dead after vtyT_kernel

    zero_rs<<<CB * CN / 256, 256, 0, stream>>>(rsb);
    gemm_kernel<<<dim3(16, 4, CB * 9), 256, 0, stream>>>(0, nf, Wq, Wk, Wv, bq, bk, bv, Qt, Ktb, Vtb);
    mix_qbar<<<CB * CN * COUT / 4 / 256, 256, 0, stream>>>(Qt, types, Qbar);
    qr2_kernel<<<dim3(CN / 8, CR * CH, CB), 256, 0, stream>>>(Qbar, rel_att, rel_pri, Qrhi, Qrlo);
    split_kt<<<CB * CT * CN * COUT / 4 / 256, 256, 0, stream>>>(Ktb, Kthi, Ktlo);
    vtyT_kernel<<<dim3(CN / 64, CH, CB * CT), 256, 0, stream>>>(Vtb, types, VtyTb);
    mT_kernel<<<CR * CH, 256, 0, stream>>>(rel_msg, MTb);
    attn2_kernel<<<dim3(CN / 64, CH, CB), 256, 0, stream>>>(Qrhi, Qrlo, Kthi, Ktlo, VtyTb, MTb,
                                                            adj, erel, types, aggb, rsb);
    gelu_gate<<<CB * CN * COUT / 4 / 256, 256, 0, stream>>>(aggb, rsb, gbuf);
    gemm_kernel<<<dim3(16, 4, CB * CT), 256, 0, stream>>>(1, gbuf, Wa, Wa, Wa, ba, ba, ba,
                                                          transb, transb, transb);
    final_ln<<<CB * CN, 256, 0, stream>>>(transb, nf, types, skip, gamma, beta, out);
}

// Round 3
// 440.259 us; speedup vs baseline: 4.6520x; 1.1735x over previous
//
#include <hip/hip_runtime.h>
#include <math.h>

// Problem constants
constexpr int CB = 4, CN = 1024, CT = 3, CR = 4, CH = 8, CDK = 32, COUT = 256;

typedef __attribute__((ext_vector_type(4))) float f32x4;
typedef __attribute__((ext_vector_type(8))) short s16x8;
typedef __attribute__((ext_vector_type(4))) _Float16 f16x4;
typedef __attribute__((ext_vector_type(8))) _Float16 f16x8;
typedef __attribute__((ext_vector_type(4))) unsigned short u16x4;
typedef __attribute__((ext_vector_type(8))) unsigned short u16x8;

__device__ inline unsigned short f2bf(float x) {
    unsigned u = __float_as_uint(x);
    unsigned r = (u + 0x7fffu + ((u >> 16) & 1u)) >> 16;
    return (unsigned short)r;
}
__device__ inline float bf2f(unsigned short b) {
    return __uint_as_float(((unsigned)b) << 16);
}

// ---------------------------------------------------------------------------
__global__ void zero_rs(float* __restrict__ rs) {
    rs[blockIdx.x * 256 + threadIdx.x] = 0.f;
}

// ---------------------------------------------------------------------------
// Generic [1024,256] x [256,256] + bias GEMM, 64x64 tile per block, 4x4/thread.
__global__ __launch_bounds__(256) void gemm_kernel(
    int mode,
    const float* __restrict__ X,
    const float* __restrict__ W0, const float* __restrict__ W1, const float* __restrict__ W2,
    const float* __restrict__ b0, const float* __restrict__ b1, const float* __restrict__ b2,
    float* __restrict__ Y0, float* __restrict__ Y1, float* __restrict__ Y2)
{
    int z = blockIdx.z;
    int b, t, w3;
    if (mode == 0) { b = z / 9; int r9 = z % 9; w3 = r9 / 3; t = r9 % 3; }
    else           { b = z / CT; t = z % CT; w3 = 0; }
    const float* Xb = X + (size_t)b * CN * COUT;
    const float* W  = (w3 == 0 ? W0 : (w3 == 1 ? W1 : W2)) + (size_t)t * COUT * COUT;
    const float* bs = (w3 == 0 ? b0 : (w3 == 1 ? b1 : b2)) + t * COUT;
    float* Y = (w3 == 0 ? Y0 : (w3 == 1 ? Y1 : Y2)) + ((size_t)b * CT + t) * CN * COUT;

    int row0 = blockIdx.x * 64, col0 = blockIdx.y * 64;
    __shared__ float As[16][65];
    __shared__ float Bsh[16][64];
    int tid = threadIdx.x;
    int tx = tid & 15, ty = tid >> 4;
    float acc[4][4] = {};

    for (int kt = 0; kt < COUT; kt += 16) {
        {
            int m = tid >> 2, k4 = (tid & 3) * 4;
            float4 xv = *(const float4*)(Xb + (size_t)(row0 + m) * COUT + kt + k4);
            As[k4 + 0][m] = xv.x; As[k4 + 1][m] = xv.y;
            As[k4 + 2][m] = xv.z; As[k4 + 3][m] = xv.w;
            int kk = tid >> 4, n4 = (tid & 15) * 4;
            *(float4*)(&Bsh[kk][n4]) = *(const float4*)(W + (size_t)(kt + kk) * COUT + col0 + n4);
        }
        __syncthreads();
        #pragma unroll
        for (int kk = 0; kk < 16; ++kk) {
            float a0 = As[kk][ty * 4 + 0], a1 = As[kk][ty * 4 + 1];
            float a2 = As[kk][ty * 4 + 2], a3 = As[kk][ty * 4 + 3];
            float4 bv = *(const float4*)(&Bsh[kk][tx * 4]);
            acc[0][0] += a0 * bv.x; acc[0][1] += a0 * bv.y; acc[0][2] += a0 * bv.z; acc[0][3] += a0 * bv.w;
            acc[1][0] += a1 * bv.x; acc[1][1] += a1 * bv.y; acc[1][2] += a1 * bv.z; acc[1][3] += a1 * bv.w;
            acc[2][0] += a2 * bv.x; acc[2][1] += a2 * bv.y; acc[2][2] += a2 * bv.z; acc[2][3] += a2 * bv.w;
            acc[3][0] += a3 * bv.x; acc[3][1] += a3 * bv.y; acc[3][2] += a3 * bv.z; acc[3][3] += a3 * bv.w;
        }
        __syncthreads();
    }
    float4 bb = *(const float4*)(bs + col0 + tx * 4);
    #pragma unroll
    for (int im = 0; im < 4; ++im) {
        float4 o;
        o.x = acc[im][0] + bb.x; o.y = acc[im][1] + bb.y;
        o.z = acc[im][2] + bb.z; o.w = acc[im][3] + bb.w;
        *(float4*)(Y + (size_t)(row0 + ty * 4 + im) * COUT + col0 + tx * 4) = o;
    }
}

// ---------------------------------------------------------------------------
// Qbar[b,i,:] = sum_t types[b,i,t] * Qt[b,t,i,:]
__global__ void mix_qbar(const float* __restrict__ Qt, const float* __restrict__ types,
                         float* __restrict__ Qbar)
{
    int idx = blockIdx.x * 256 + threadIdx.x;
    int bi = idx >> 6;
    int o4 = (idx & 63) * 4;
    int b = bi >> 10;
    const float* tp = types + (size_t)bi * CT;
    float t0 = tp[0], t1 = tp[1], t2 = tp[2];
    size_t nbase = ((size_t)b * CT) * CN * COUT + (size_t)(bi & 1023) * COUT + o4;
    float4 q0 = *(const float4*)(Qt + nbase);
    float4 q1 = *(const float4*)(Qt + nbase + (size_t)CN * COUT);
    float4 q2 = *(const float4*)(Qt + nbase + 2 * (size_t)CN * COUT);
    float4 o;
    o.x = t0 * q0.x + t1 * q1.x + t2 * q2.x;
    o.y = t0 * q0.y + t1 * q1.y + t2 * q2.y;
    o.z = t0 * q0.z + t1 * q1.z + t2 * q2.z;
    o.w = t0 * q0.w + t1 * q1.w + t2 * q2.w;
    *(float4*)(Qbar + (size_t)bi * COUT + o4) = o;
}

// ---------------------------------------------------------------------------
// Qr[b,r,h,i,d] = (pri[r,h]/sqrt(dk)) * sum_e rel_att[r,h,d,e]*Qbar[b,i,h*32+e]
// bf16 hi/lo split, h-major layout for contiguous wave loads.
__global__ __launch_bounds__(256) void qr3_kernel(const float* __restrict__ Qbar,
                                                  const float* __restrict__ rel_att,
                                                  const float* __restrict__ rel_pri,
                                                  unsigned short* __restrict__ Qrhi,
                                                  unsigned short* __restrict__ Qrlo)
{
    int i0 = blockIdx.x * 8;
    int rh = blockIdx.y; int r = rh >> 3, h = rh & 7;
    int b = blockIdx.z;
    __shared__ float A_s[32][33];
    __shared__ float q_s[8][32];
    int tid = threadIdx.x;
    {
        int f = tid * 4; int d = f >> 5, e = f & 31;
        float4 v = *(const float4*)(rel_att + ((size_t)rh * 32 + d) * 32 + e);
        A_s[d][e] = v.x; A_s[d][e + 1] = v.y; A_s[d][e + 2] = v.z; A_s[d][e + 3] = v.w;
        int ii = tid >> 5, ee = tid & 31;
        q_s[ii][ee] = Qbar[((size_t)b * CN + i0 + ii) * COUT + h * CDK + ee];
    }
    __syncthreads();
    int d = tid & 31, ii = tid >> 5;
    float acc = 0.f;
    #pragma unroll 8
    for (int e = 0; e < 32; ++e) acc += A_s[d][e] * q_s[ii][e];
    const float inv_sqrt = 0.17677669529663687f;
    float v = acc * rel_pri[rh] * inv_sqrt;
    unsigned short hb = f2bf(v);
    float lo = v - bf2f(hb);
    size_t oidx = ((((size_t)b * CR + r) * CH + h) * CN + i0 + ii) * CDK + d;
    Qrhi[oidx] = hb;
    Qrlo[oidx] = f2bf(lo);
}

// ---------------------------------------------------------------------------
// Per (b,j): Kbar = sum_s ty_s*Kt_s (bf16 hi/lo split) and Kty_s = bf16(ty_s*Kt_s),
// all written h-major: [b][h][j][32] / [(b,s)][h][j][32].
__global__ __launch_bounds__(256) void prep_k(const float* __restrict__ Kt,
                                              const float* __restrict__ types,
                                              unsigned short* __restrict__ Kbh,
                                              unsigned short* __restrict__ Kbl,
                                              unsigned short* __restrict__ Kty)
{
    int b = blockIdx.y;
    int j = blockIdx.x * 8 + (threadIdx.x >> 5);
    int c = threadIdx.x & 31;
    int h = c >> 2, d0 = (c & 3) * 8;
    const float* tp = types + ((size_t)b * CN + j) * CT;
    float kb[8];
    #pragma unroll
    for (int k = 0; k < 8; ++k) kb[k] = 0.f;
    #pragma unroll
    for (int s = 0; s < 3; ++s) {
        float ty = tp[s];
        const float* src = Kt + (((size_t)(b * 3 + s)) * CN + j) * COUT + c * 8;
        f32x4 a0 = *(const f32x4*)(src);
        f32x4 a1 = *(const f32x4*)(src + 4);
        u16x8 kt8;
        #pragma unroll
        for (int k = 0; k < 4; ++k) {
            float v0 = ty * a0[k], v1 = ty * a1[k];
            kt8[k] = f2bf(v0); kt8[4 + k] = f2bf(v1);
            kb[k] += v0; kb[4 + k] += v1;
        }
        *(u16x8*)(Kty + (((size_t)(b * 3 + s) * CH + h) * CN + j) * CDK + d0) = kt8;
    }
    u16x8 hv, lv;
    #pragma unroll
    for (int k = 0; k < 8; ++k) {
        unsigned short hb = f2bf(kb[k]);
        hv[k] = hb; lv[k] = f2bf(kb[k] - bf2f(hb));
    }
    *(u16x8*)(Kbh + (((size_t)b * CH + h) * CN + j) * CDK + d0) = hv;
    *(u16x8*)(Kbl + (((size_t)b * CH + h) * CN + j) * CDK + d0) = lv;
}

// ---------------------------------------------------------------------------
// VT[(b,s)][h][e][j] = Vt[b,s,j,h*32+e]  (f16, j contiguous; NO types factor)
__global__ __launch_bounds__(256) void vT_kernel(const float* __restrict__ Vt,
                                                 _Float16* __restrict__ VT)
{
    int j0 = blockIdx.x * 64; int h = blockIdx.y; int bs = blockIdx.z;
    __shared__ float tile[32][72];
    int t = threadIdx.x;
    int jj = t >> 2, e8 = (t & 3) * 8;
    const float* src = Vt + ((size_t)bs * CN + j0 + jj) * COUT + h * CDK + e8;
    f32x4 v0 = *(const f32x4*)(src);
    f32x4 v1 = *(const f32x4*)(src + 4);
    #pragma unroll
    for (int k = 0; k < 4; ++k) { tile[e8 + k][jj] = v0[k]; tile[e8 + 4 + k][jj] = v1[k]; }
    __syncthreads();
    int e = t >> 3, jr = (t & 7) * 8;
    f16x8 o;
    #pragma unroll
    for (int k = 0; k < 8; ++k) o[k] = (_Float16)tile[e][jr + k];
    *(f16x8*)(VT + (((size_t)bs * CH + h) * CDK + e) * CN + j0 + jr) = o;
}

// ---------------------------------------------------------------------------
// MT[r,h,e,e'] = rel_msg[r,h,e',e]  (f16)
__global__ void mT_kernel(const float* __restrict__ rel_msg, _Float16* __restrict__ MT)
{
    int rh = blockIdx.x; int t = threadIdx.x;
    int e = t >> 3, ep4 = (t & 7) * 4;
    f16x4 o;
    #pragma unroll
    for (int k = 0; k < 4; ++k)
        o[k] = (_Float16)rel_msg[((size_t)rh * 32 + ep4 + k) * 32 + e];
    *(f16x4*)(MT + ((size_t)rh * 32 + e) * 32 + ep4) = o;
}

// ---------------------------------------------------------------------------
// coefT[b][j][i][r] = adj[b,i,j] * erel[b,i,j,r]  (fp32, transposed for coalesced
// j-at-quads / i-at-lanes access in attention)
__global__ __launch_bounds__(256) void coef_t(const float* __restrict__ adj,
                                              const float* __restrict__ erel,
                                              float* __restrict__ coefT)
{
    int b = blockIdx.z; int i0 = blockIdx.y * 32; int j0 = blockIdx.x * 32;
    __shared__ float tile[32][132];
    int t = threadIdx.x;
    {
        int ii = t >> 3, jc = t & 7;
        size_t arow = ((size_t)b * CN + i0 + ii) * CN + j0;
        f32x4 av = *(const f32x4*)(adj + arow + jc * 4);
        #pragma unroll
        for (int kk = 0; kk < 4; ++kk) {
            int j = jc * 4 + kk;
            f32x4 ev = *(const f32x4*)(erel + (arow + j) * 4);
            float a = av[kk];
            f32x4 cv;
            cv[0] = ev[0] * a; cv[1] = ev[1] * a; cv[2] = ev[2] * a; cv[3] = ev[3] * a;
            *(f32x4*)&tile[j][ii * 4] = cv;
        }
    }
    __syncthreads();
    {
        int jj = t >> 3, ic = t & 7;
        size_t orow = ((size_t)b * CN + j0 + jj) * CN + i0;
        #pragma unroll
        for (int kk = 0; kk < 4; ++kk)
            *(f32x4*)(coefT + (orow + ic * 4 + kk) * 4) = *(const f32x4*)&tile[jj][(ic * 4 + kk) * 4];
    }
}

// ---------------------------------------------------------------------------
// MFMA flash attention v3. Grid (16 itile64, 8 h, b*2+part); 4 waves/block;
// j-split halves merged later (no-max softmax => partials just add).
// Per 16-j step: Dbar_r = Kbar.Qr_r (bf16 split, 12 MFMA) -> logits/exp;
// Dp_sr = Kty_s.Qr_r hi-only (12 MFMA); PV (24 f16 MFMA). V staged via LDS dbuf.
__global__ __launch_bounds__(256, 3) void attn3_kernel(
    const unsigned short* __restrict__ Qrhi, const unsigned short* __restrict__ Qrlo,
    const unsigned short* __restrict__ Kbh,  const unsigned short* __restrict__ Kbl,
    const unsigned short* __restrict__ Kty,
    const _Float16* __restrict__ VT,
    const float* __restrict__ coefT,
    float* __restrict__ Upart,   // [b][h][itile16][part][8][256]
    float* __restrict__ lbuf,    // [part][b][h][i]
    float* __restrict__ rowsum)  // [b][i]
{
    const int h = blockIdx.y;
    const int z = blockIdx.z; const int b = z >> 1, part = z & 1;
    const int tid = threadIdx.x;
    const int wave = tid >> 6, lane = tid & 63;
    const int col = lane & 15, quad = lane >> 4;
    const int i = blockIdx.x * 64 + wave * 16 + col;
    const int jbase = part * 512;

    __shared__ _Float16 vs[2][3][32][20];

    // loop-invariant Qr B-frags
    s16x8 qh[4], ql[4];
    #pragma unroll
    for (int r = 0; r < 4; ++r) {
        size_t off = ((((size_t)b * CR + r) * CH + h) * CN + i) * CDK + quad * 8;
        qh[r] = *(const s16x8*)(Qrhi + off);
        ql[r] = *(const s16x8*)(Qrlo + off);
    }

    // staging assignment: thread -> (s loop, e_st, jc_st), one b32 per s per tile
    const int e_st = tid >> 3, jc_st = tid & 7;
    size_t vtb[3];
    #pragma unroll
    for (int s = 0; s < 3; ++s)
        vtb[s] = (((size_t)(b * 3 + s) * CH + h) * CDK + e_st) * CN + jc_st * 2;

    // prologue: stage tile 0
    #pragma unroll
    for (int s = 0; s < 3; ++s)
        *(unsigned*)&vs[0][s][e_st][jc_st * 2] = *(const unsigned*)(VT + vtb[s] + jbase);
    __syncthreads();

    f32x4 U[4][2];
    #pragma unroll
    for (int r = 0; r < 4; ++r) { U[r][0] = (f32x4){0.f,0.f,0.f,0.f}; U[r][1] = (f32x4){0.f,0.f,0.f,0.f}; }
    float lpart = 0.f, rspart = 0.f;

    const size_t kbbase = (((size_t)b * CH + h) * CN + col) * CDK + quad * 8;
    size_t ktbase[3];
    #pragma unroll
    for (int s = 0; s < 3; ++s)
        ktbase[s] = (((size_t)(b * 3 + s) * CH + h) * CN + col) * CDK + quad * 8;

    #pragma unroll 1
    for (int js = 0; js < 32; ++js) {
        const int j0 = jbase + js * 16;
        const int buf = js & 1;
        // prefetch next V tile into regs
        const int jn = jbase + ((js + 1 < 32) ? (js + 1) * 16 : js * 16);
        unsigned pf0 = *(const unsigned*)(VT + vtb[0] + jn);
        unsigned pf1 = *(const unsigned*)(VT + vtb[1] + jn);
        unsigned pf2 = *(const unsigned*)(VT + vtb[2] + jn);

        // wave loads (all contiguous-per-wave after re-layout)
        s16x8 kbh_ = *(const s16x8*)(Kbh + kbbase + (size_t)j0 * CDK);
        s16x8 kbl_ = *(const s16x8*)(Kbl + kbbase + (size_t)j0 * CDK);
        s16x8 kt[3];
        #pragma unroll
        for (int s = 0; s < 3; ++s)
            kt[s] = *(const s16x8*)(Kty + ktbase[s] + (size_t)j0 * CDK);
        f32x4 cf[4];
        #pragma unroll
        for (int reg = 0; reg < 4; ++reg)
            cf[reg] = *(const f32x4*)(coefT + (((size_t)b * CN + j0 + quad * 4 + reg) * CN + i) * 4);

        // Dbar (precision path for logits/row_sum)
        f32x4 Db[4];
        #pragma unroll
        for (int r = 0; r < 4; ++r) {
            f32x4 d = {0.f, 0.f, 0.f, 0.f};
            d = __builtin_amdgcn_mfma_f32_16x16x32_bf16(kbl_, qh[r], d, 0, 0, 0);
            d = __builtin_amdgcn_mfma_f32_16x16x32_bf16(kbh_, ql[r], d, 0, 0, 0);
            d = __builtin_amdgcn_mfma_f32_16x16x32_bf16(kbh_, qh[r], d, 0, 0, 0);
            Db[r] = d;
        }
        // logits + exp (no running max: |L| << 88)
        float P[4];
        #pragma unroll
        for (int reg = 0; reg < 4; ++reg) {
            float L = cf[reg][0] * Db[0][reg] + cf[reg][1] * Db[1][reg]
                    + cf[reg][2] * Db[2][reg] + cf[reg][3] * Db[3][reg];
            rspart += L;
            P[reg] = __expf(L);
            lpart += P[reg];
        }
        // per-s PV
        #pragma unroll
        for (int s = 0; s < 3; ++s) {
            f32x4 Dp[4];
            #pragma unroll
            for (int r = 0; r < 4; ++r) {
                f32x4 d = {0.f, 0.f, 0.f, 0.f};
                Dp[r] = __builtin_amdgcn_mfma_f32_16x16x32_bf16(kt[s], qh[r], d, 0, 0, 0);
            }
            f16x4 v0 = *(const f16x4*)&vs[buf][s][col][quad * 4];
            f16x4 v1 = *(const f16x4*)&vs[buf][s][col + 16][quad * 4];
            #pragma unroll
            for (int r = 0; r < 4; ++r) {
                f16x4 w;
                w[0] = (_Float16)(P[0] * cf[0][r] * Dp[r][0]);
                w[1] = (_Float16)(P[1] * cf[1][r] * Dp[r][1]);
                w[2] = (_Float16)(P[2] * cf[2][r] * Dp[r][2]);
                w[3] = (_Float16)(P[3] * cf[3][r] * Dp[r][3]);
                U[r][0] = __builtin_amdgcn_mfma_f32_16x16x16f16(v0, w, U[r][0], 0, 0, 0);
                U[r][1] = __builtin_amdgcn_mfma_f32_16x16x16f16(v1, w, U[r][1], 0, 0, 0);
            }
        }
        // stage next tile
        *(unsigned*)&vs[buf ^ 1][0][e_st][jc_st * 2] = pf0;
        *(unsigned*)&vs[buf ^ 1][1][e_st][jc_st * 2] = pf1;
        *(unsigned*)&vs[buf ^ 1][2][e_st][jc_st * 2] = pf2;
        __syncthreads();
    }

    // reductions over quads
    float l = lpart;  l += __shfl_xor(l, 16);  l += __shfl_xor(l, 32);
    float rv = rspart; rv += __shfl_xor(rv, 16); rv += __shfl_xor(rv, 32);
    if (quad == 0) {
        lbuf[(((size_t)part * CB + b) * CH + h) * CN + i] = l;
        atomicAdd(rowsum + (size_t)b * CN + i, rv);
    }
    // write U partials (coalesced layout, per-lane mapping preserved for merge)
    int itile = blockIdx.x * 4 + wave;
    size_t ub = ((((size_t)(b * CH + h) * 64 + itile) * 2 + part)) * 2048;
    #pragma unroll
    for (int r = 0; r < 4; ++r)
        #pragma unroll
        for (int eh = 0; eh < 2; ++eh)
            *(f32x4*)(Upart + ub + (size_t)(r * 2 + eh) * 256 + lane * 4) = U[r][eh];
}

// ---------------------------------------------------------------------------
// Merge j-split partials, normalize by l, apply rel_msg via MFMA, write agg.
__global__ __launch_bounds__(256) void merge_kernel(
    const float* __restrict__ Upart, const float* __restrict__ lbuf,
    const _Float16* __restrict__ MT, float* __restrict__ agg)
{
    const int h = blockIdx.y, b = blockIdx.z;
    const int tid = threadIdx.x;
    const int wave = tid >> 6, lane = tid & 63;
    const int col = lane & 15, quad = lane >> 4;
    const int itile = blockIdx.x * 4 + wave;
    const int i = itile * 16 + col;

    size_t ub = ((size_t)(b * CH + h) * 64 + itile) * 2 * 2048;
    f32x4 U[4][2];
    #pragma unroll
    for (int r = 0; r < 4; ++r)
        #pragma unroll
        for (int eh = 0; eh < 2; ++eh) {
            f32x4 a = *(const f32x4*)(Upart + ub + (size_t)(r * 2 + eh) * 256 + lane * 4);
            f32x4 c = *(const f32x4*)(Upart + ub + 2048 + (size_t)(r * 2 + eh) * 256 + lane * 4);
            U[r][eh] = a + c;
        }
    float l = lbuf[(((size_t)0 * CB + b) * CH + h) * CN + i]
            + lbuf[(((size_t)1 * CB + b) * CH + h) * CN + i];
    float il = 1.f / l;
    f16x4 Uh[4][2];
    #pragma unroll
    for (int r = 0; r < 4; ++r)
        #pragma unroll
        for (int eh = 0; eh < 2; ++eh) {
            Uh[r][eh][0] = (_Float16)(U[r][eh][0] * il);
            Uh[r][eh][1] = (_Float16)(U[r][eh][1] * il);
            Uh[r][eh][2] = (_Float16)(U[r][eh][2] * il);
            Uh[r][eh][3] = (_Float16)(U[r][eh][3] * il);
        }
    #pragma unroll
    for (int eo = 0; eo < 2; ++eo) {
        f32x4 acc = {0.f, 0.f, 0.f, 0.f};
        #pragma unroll
        for (int r = 0; r < 4; ++r)
            #pragma unroll
            for (int ep = 0; ep < 2; ++ep) {
                f16x4 mt = *(const f16x4*)(MT + ((size_t)(r * 8 + h) * 32 + eo * 16 + col) * 32
                                               + ep * 16 + quad * 4);
                acc = __builtin_amdgcn_mfma_f32_16x16x16f16(mt, Uh[r][ep], acc, 0, 0, 0);
            }
        *(f32x4*)(agg + ((size_t)b * CN + i) * COUT + h * CDK + eo * 16 + quad * 4) = acc;
    }
}

// ---------------------------------------------------------------------------
__global__ void gelu_gate(const float* __restrict__ agg, const float* __restrict__ row_sum,
                          float* __restrict__ gout)
{
    int idx = blockIdx.x * 256 + threadIdx.x;
    int bi = idx >> 6;
    float rsv = row_sum[bi];
    float4 v = *(const float4*)(agg + (size_t)idx * 4);
    if (!(rsv > 1e-6f)) { v.x = 0.f; v.y = 0.f; v.z = 0.f; v.w = 0.f; }
    const float is2 = 0.70710678118654752f;
    float4 o;
    o.x = 0.5f * v.x * (1.f + erff(v.x * is2));
    o.y = 0.5f * v.y * (1.f + erff(v.y * is2));
    o.z = 0.5f * v.z * (1.f + erff(v.z * is2));
    o.w = 0.5f * v.w * (1.f + erff(v.w * is2));
    *(float4*)(gout + (size_t)idx * 4) = o;
}

// ---------------------------------------------------------------------------
__global__ __launch_bounds__(256) void final_ln(
    const float* __restrict__ trans, const float* __restrict__ x,
    const float* __restrict__ types, const float* __restrict__ skip,
    const float* __restrict__ gamma, const float* __restrict__ beta,
    float* __restrict__ out)
{
    int bi = blockIdx.x;
    int b = bi >> 10;
    int i = bi & 1023;
    int o = threadIdx.x;
    __shared__ float red[4];
    float xo = x[(size_t)bi * COUT + o];
    float accum = 0.f;
    #pragma unroll 1
    for (int t = 0; t < CT; ++t) {
        float al = 1.f / (1.f + __expf(-skip[t]));
        float tr = trans[(((size_t)b * CT + t) * CN + i) * COUT + o];
        float res = tr * al + xo * (1.f - al);
        float v = res;
        #pragma unroll
        for (int mk = 1; mk < 64; mk <<= 1) v += __shfl_xor(v, mk);
        __syncthreads();
        if ((o & 63) == 0) red[o >> 6] = v;
        __syncthreads();
        float mu = (red[0] + red[1] + red[2] + red[3]) * (1.f / COUT);
        float dc = res - mu;
        float v2 = dc * dc;
        #pragma unroll
        for (int mk = 1; mk < 64; mk <<= 1) v2 += __shfl_xor(v2, mk);
        __syncthreads();
        if ((o & 63) == 0) red[o >> 6] = v2;
        __syncthreads();
        float var = (red[0] + red[1] + red[2] + red[3]) * (1.f / COUT);
        float ln = dc * rsqrtf(var + 1e-5f) * gamma[t * COUT + o] + beta[t * COUT + o];
        accum += types[(size_t)bi * CT + t] * ln;
    }
    out[(size_t)bi * COUT + o] = accum;
}

// ---------------------------------------------------------------------------
extern "C" void kernel_launch(void* const* d_in, const int* in_sizes, int n_in,
                              void* d_out, int out_size, void* d_ws, size_t ws_size,
                              hipStream_t stream)
{
    (void)in_sizes; (void)n_in; (void)out_size; (void)ws_size;
    const float* nf      = (const float*)d_in[0];
    const float* types   = (const float*)d_in[1];
    const float* adj     = (const float*)d_in[2];
    const float* erel    = (const float*)d_in[3];
    const float* Wq      = (const float*)d_in[4];
    const float* bq      = (const float*)d_in[5];
    const float* Wk      = (const float*)d_in[6];
    const float* bk      = (const float*)d_in[7];
    const float* Wv      = (const float*)d_in[8];
    const float* bv      = (const float*)d_in[9];
    const float* Wa      = (const float*)d_in[10];
    const float* ba      = (const float*)d_in[11];
    const float* rel_pri = (const float*)d_in[12];
    const float* rel_att = (const float*)d_in[13];
    const float* rel_msg = (const float*)d_in[14];
    const float* skip    = (const float*)d_in[15];
    const float* gamma   = (const float*)d_in[16];
    const float* beta    = (const float*)d_in[17];
    float* out = (float*)d_out;

    float* ws = (float*)d_ws;
    size_t o = 0;
    float* pool0 = ws + o; o += 3 * (size_t)CB * CT * CN * COUT;   // 9.44M f32
    float* Qt  = pool0;
    float* Ktb = pool0 + (size_t)CB * CT * CN * COUT;
    float* Vtb = pool0 + 2 * (size_t)CB * CT * CN * COUT;
    float* Qbar = ws + o; o += (size_t)CB * CN * COUT;
    float* aggb = ws + o; o += (size_t)CB * CN * COUT;
    float* rsb  = ws + o; o += (size_t)CB * CN;
    float* lbufp = ws + o; o += 2 * (size_t)CB * CH * CN;
    unsigned short* Qrhi = (unsigned short*)(ws + o); o += (size_t)CB * CR * CN * COUT / 2;
    unsigned short* Qrlo = (unsigned short*)(ws + o); o += (size_t)CB * CR * CN * COUT / 2;
    unsigned short* Kbh  = (unsigned short*)(ws + o); o += (size_t)CB * CH * CN * CDK / 2;
    unsigned short* Kbl  = (unsigned short*)(ws + o); o += (size_t)CB * CH * CN * CDK / 2;
    unsigned short* Kty  = (unsigned short*)(ws + o); o += (size_t)CB * CT * CH * CN * CDK / 2;
    _Float16* VTb = (_Float16*)(ws + o);              o += (size_t)CB * CT * CH * CDK * CN / 2;
    _Float16* MTb = (_Float16*)(ws + o);              o += (size_t)CR * CH * CDK * CDK / 2;
    float* coefT = ws + o; o += (size_t)CB * CN * CN * CR;   // 16.8M f32
    // overlays on pool0 (Qt/Ktb/Vtb all dead by attn3)
    float* Upart  = pool0;                               // 8.39M f32
    float* gbuf   = pool0;                               // after merge
    float* transb = pool0 + (size_t)CB * CN * COUT;

    zero_rs<<<CB * CN / 256, 256, 0, stream>>>(rsb);
    gemm_kernel<<<dim3(16, 4, CB * 9), 256, 0, stream>>>(0, nf, Wq, Wk, Wv, bq, bk, bv, Qt, Ktb, Vtb);
    coef_t<<<dim3(32, 32, CB), 256, 0, stream>>>(adj, erel, coefT);
    mix_qbar<<<CB * CN * COUT / 4 / 256, 256, 0, stream>>>(Qt, types, Qbar);
    qr3_kernel<<<dim3(CN / 8, CR * CH, CB), 256, 0, stream>>>(Qbar, rel_att, rel_pri, Qrhi, Qrlo);
    prep_k<<<dim3(CN / 8, CB), 256, 0, stream>>>(Ktb, types, Kbh, Kbl, Kty);
    vT_kernel<<<dim3(CN / 64, CH, CB * CT), 256, 0, stream>>>(Vtb, VTb);
    mT_kernel<<<CR * CH, 256, 0, stream>>>(rel_msg, MTb);
    attn3_kernel<<<dim3(16, CH, CB * 2), 256, 0, stream>>>(Qrhi, Qrlo, Kbh, Kbl, Kty, VTb, coefT,
                                                           Upart, lbufp, rsb);
    merge_kernel<<<dim3(16, CH, CB), 256, 0, stream>>>(Upart, lbufp, MTb, aggb);
    gelu_gate<<<CB * CN * COUT / 4 / 256, 256, 0, stream>>>(aggb, rsb, gbuf);
    gemm_kernel<<<dim3(16, 4, CB * CT), 256, 0, stream>>>(1, gbuf, Wa, Wa, Wa, ba, ba, ba,
                                                          transb, transb, transb);
    final_ln<<<CB * CN, 256, 0, stream>>>(transb, nf, types, skip, gamma, beta, out);
}

// Round 4
// 383.075 us; speedup vs baseline: 5.3464x; 1.1493x over previous
//
#include <hip/hip_runtime.h>
#include <math.h>

// Problem constants
constexpr int CB = 4, CN = 1024, CT = 3, CR = 4, CH = 8, CDK = 32, COUT = 256;

typedef __attribute__((ext_vector_type(4))) float f32x4;
typedef __attribute__((ext_vector_type(8))) short s16x8;
typedef __attribute__((ext_vector_type(4))) _Float16 f16x4;
typedef __attribute__((ext_vector_type(8))) _Float16 f16x8;
typedef __attribute__((ext_vector_type(4))) unsigned short u16x4;
typedef __attribute__((ext_vector_type(8))) unsigned short u16x8;

__device__ inline unsigned short f2bf(float x) {
    unsigned u = __float_as_uint(x);
    unsigned r = (u + 0x7fffu + ((u >> 16) & 1u)) >> 16;
    return (unsigned short)r;
}
__device__ inline float bf2f(unsigned short b) {
    return __uint_as_float(((unsigned)b) << 16);
}

// ---------------------------------------------------------------------------
__global__ void zero_rs(float* __restrict__ rs) {
    rs[blockIdx.x * 256 + threadIdx.x] = 0.f;
}

// ---------------------------------------------------------------------------
// fp32 -> bf16 hi/lo split (flat)
__global__ void splitx(const float* __restrict__ X,
                       unsigned short* __restrict__ Xh, unsigned short* __restrict__ Xl)
{
    size_t idx = ((size_t)blockIdx.x * 256 + threadIdx.x) * 4;
    f32x4 v = *(const f32x4*)(X + idx);
    u16x4 hv, lv;
    #pragma unroll
    for (int k = 0; k < 4; ++k) {
        unsigned short hb = f2bf(v[k]);
        hv[k] = hb;
        lv[k] = f2bf(v[k] - bf2f(hb));
    }
    *(u16x4*)(Xh + idx) = hv;
    *(u16x4*)(Xl + idx) = lv;
}

// ---------------------------------------------------------------------------
// Weight transpose+split: WT[z][n][k] = W_z[k][n], bf16 hi/lo.
// z: 0..8 = {Wq,Wk,Wv}x{t}, 9..11 = Wa[t]. grid (8,8,12).
__global__ __launch_bounds__(256) void wsplit(
    const float* __restrict__ Wq, const float* __restrict__ Wk,
    const float* __restrict__ Wv, const float* __restrict__ Wa,
    unsigned short* __restrict__ WTh, unsigned short* __restrict__ WTl)
{
    int z = blockIdx.z;
    int t = z % 3;
    const float* W;
    if (z < 9) { int w3 = z / 3; W = (w3 == 0 ? Wq : (w3 == 1 ? Wk : Wv)); }
    else W = Wa;
    W += (size_t)t * COUT * COUT;
    int k0 = blockIdx.x * 32, n0 = blockIdx.y * 32;
    __shared__ float tl[32][33];
    int tid = threadIdx.x;
    {
        int k = tid >> 3, n4 = (tid & 7) * 4;
        f32x4 v = *(const f32x4*)(W + (size_t)(k0 + k) * COUT + n0 + n4);
        tl[n4 + 0][k] = v[0]; tl[n4 + 1][k] = v[1];
        tl[n4 + 2][k] = v[2]; tl[n4 + 3][k] = v[3];
    }
    __syncthreads();
    int n = tid >> 3, k4 = (tid & 7) * 4;
    u16x4 hv, lv;
    #pragma unroll
    for (int j = 0; j < 4; ++j) {
        float x = tl[n][k4 + j];
        unsigned short hb = f2bf(x);
        hv[j] = hb; lv[j] = f2bf(x - bf2f(hb));
    }
    size_t off = (size_t)z * COUT * COUT + (size_t)(n0 + n) * COUT + k0 + k4;
    *(u16x4*)(WTh + off) = hv;
    *(u16x4*)(WTl + off) = lv;
}

// ---------------------------------------------------------------------------
// bf16-split MFMA GEMM: Y[1024,256] = X[1024,256] @ W[256,256] + bias, fp32-ish
// accuracy via 3-product hi/lo split. 128x128 tile/block, 4 waves 64x64 each.
__global__ __launch_bounds__(256) void mfma_gemm(
    int mode,
    const unsigned short* __restrict__ Ah, const unsigned short* __restrict__ Al,
    const unsigned short* __restrict__ WTh, const unsigned short* __restrict__ WTl,
    const float* __restrict__ bq, const float* __restrict__ bk,
    const float* __restrict__ bv, const float* __restrict__ ba,
    float* __restrict__ Y0, float* __restrict__ Y1, float* __restrict__ Y2)
{
    int z = blockIdx.z;
    int b, t, widx;
    const float* bias;
    float* Y;
    if (mode == 0) {
        b = z / 9; int r9 = z % 9; int w3 = r9 / 3; t = r9 % 3;
        widx = w3 * 3 + t;
        bias = (w3 == 0 ? bq : (w3 == 1 ? bk : bv)) + t * COUT;
        Y = (w3 == 0 ? Y0 : (w3 == 1 ? Y1 : Y2)) + ((size_t)b * CT + t) * CN * COUT;
    } else {
        b = z / CT; t = z % CT;
        widx = 9 + t;
        bias = ba + t * COUT;
        Y = Y0 + ((size_t)b * CT + t) * CN * COUT;
    }
    const unsigned short* Ahb = Ah + (size_t)b * CN * COUT;
    const unsigned short* Alb = Al + (size_t)b * CN * COUT;
    const unsigned short* Bhb = WTh + (size_t)widx * COUT * COUT;
    const unsigned short* Blb = WTl + (size_t)widx * COUT * COUT;

    const int M0 = blockIdx.x * 128, N0 = blockIdx.y * 128;
    __shared__ unsigned short As[2][128][40];
    __shared__ unsigned short Bs[2][128][40];
    const int tid = threadIdx.x;
    const int wave = tid >> 6, lane = tid & 63;
    const int wm = wave & 1, wn = wave >> 1;
    const int col = lane & 15, quad = lane >> 4;

    f32x4 acc[4][4];
    #pragma unroll
    for (int mt = 0; mt < 4; ++mt)
        #pragma unroll
        for (int nt = 0; nt < 4; ++nt) acc[mt][nt] = (f32x4){0.f, 0.f, 0.f, 0.f};

    for (int kt = 0; kt < COUT; kt += 32) {
        #pragma unroll
        for (int q = 0; q < 2; ++q) {
            int f = q * 256 + tid;
            int m = f >> 2, kc = (f & 3) * 8;
            *(u16x8*)&As[0][m][kc] = *(const u16x8*)(Ahb + (size_t)(M0 + m) * COUT + kt + kc);
            *(u16x8*)&As[1][m][kc] = *(const u16x8*)(Alb + (size_t)(M0 + m) * COUT + kt + kc);
            *(u16x8*)&Bs[0][m][kc] = *(const u16x8*)(Bhb + (size_t)(N0 + m) * COUT + kt + kc);
            *(u16x8*)&Bs[1][m][kc] = *(const u16x8*)(Blb + (size_t)(N0 + m) * COUT + kt + kc);
        }
        __syncthreads();
        s16x8 ah[4], al4[4], bh[4], bl4[4];
        #pragma unroll
        for (int mt = 0; mt < 4; ++mt) {
            ah[mt]  = *(const s16x8*)&As[0][wm * 64 + mt * 16 + col][quad * 8];
            al4[mt] = *(const s16x8*)&As[1][wm * 64 + mt * 16 + col][quad * 8];
        }
        #pragma unroll
        for (int nt = 0; nt < 4; ++nt) {
            bh[nt]  = *(const s16x8*)&Bs[0][wn * 64 + nt * 16 + col][quad * 8];
            bl4[nt] = *(const s16x8*)&Bs[1][wn * 64 + nt * 16 + col][quad * 8];
        }
        #pragma unroll
        for (int mt = 0; mt < 4; ++mt)
            #pragma unroll
            for (int nt = 0; nt < 4; ++nt) {
                acc[mt][nt] = __builtin_amdgcn_mfma_f32_16x16x32_bf16(al4[mt], bh[nt], acc[mt][nt], 0, 0, 0);
                acc[mt][nt] = __builtin_amdgcn_mfma_f32_16x16x32_bf16(ah[mt], bl4[nt], acc[mt][nt], 0, 0, 0);
                acc[mt][nt] = __builtin_amdgcn_mfma_f32_16x16x32_bf16(ah[mt], bh[nt], acc[mt][nt], 0, 0, 0);
            }
        __syncthreads();
    }
    float bb[4];
    #pragma unroll
    for (int nt = 0; nt < 4; ++nt) bb[nt] = bias[N0 + wn * 64 + nt * 16 + col];
    #pragma unroll
    for (int mt = 0; mt < 4; ++mt)
        #pragma unroll
        for (int nt = 0; nt < 4; ++nt) {
            int n = N0 + wn * 64 + nt * 16 + col;
            #pragma unroll
            for (int reg = 0; reg < 4; ++reg) {
                int m = M0 + wm * 64 + mt * 16 + quad * 4 + reg;
                Y[(size_t)m * COUT + n] = acc[mt][nt][reg] + bb[nt];
            }
        }
}

// ---------------------------------------------------------------------------
// Qbar[b,i,:] = sum_t types[b,i,t] * Qt[b,t,i,:]
__global__ void mix_qbar(const float* __restrict__ Qt, const float* __restrict__ types,
                         float* __restrict__ Qbar)
{
    int idx = blockIdx.x * 256 + threadIdx.x;
    int bi = idx >> 6;
    int o4 = (idx & 63) * 4;
    int b = bi >> 10;
    const float* tp = types + (size_t)bi * CT;
    float t0 = tp[0], t1 = tp[1], t2 = tp[2];
    size_t nbase = ((size_t)b * CT) * CN * COUT + (size_t)(bi & 1023) * COUT + o4;
    float4 q0 = *(const float4*)(Qt + nbase);
    float4 q1 = *(const float4*)(Qt + nbase + (size_t)CN * COUT);
    float4 q2 = *(const float4*)(Qt + nbase + 2 * (size_t)CN * COUT);
    float4 o;
    o.x = t0 * q0.x + t1 * q1.x + t2 * q2.x;
    o.y = t0 * q0.y + t1 * q1.y + t2 * q2.y;
    o.z = t0 * q0.z + t1 * q1.z + t2 * q2.z;
    o.w = t0 * q0.w + t1 * q1.w + t2 * q2.w;
    *(float4*)(Qbar + (size_t)bi * COUT + o4) = o;
}

// ---------------------------------------------------------------------------
// Qr[b,r,h,i,d] = (pri[r,h]/sqrt(dk)) * sum_e rel_att[r,h,d,e]*Qbar[b,i,h*32+e]
// bf16 hi/lo split, h-major layout for contiguous wave loads.
__global__ __launch_bounds__(256) void qr3_kernel(const float* __restrict__ Qbar,
                                                  const float* __restrict__ rel_att,
                                                  const float* __restrict__ rel_pri,
                                                  unsigned short* __restrict__ Qrhi,
                                                  unsigned short* __restrict__ Qrlo)
{
    int i0 = blockIdx.x * 8;
    int rh = blockIdx.y; int r = rh >> 3, h = rh & 7;
    int b = blockIdx.z;
    __shared__ float A_s[32][33];
    __shared__ float q_s[8][32];
    int tid = threadIdx.x;
    {
        int f = tid * 4; int d = f >> 5, e = f & 31;
        float4 v = *(const float4*)(rel_att + ((size_t)rh * 32 + d) * 32 + e);
        A_s[d][e] = v.x; A_s[d][e + 1] = v.y; A_s[d][e + 2] = v.z; A_s[d][e + 3] = v.w;
        int ii = tid >> 5, ee = tid & 31;
        q_s[ii][ee] = Qbar[((size_t)b * CN + i0 + ii) * COUT + h * CDK + ee];
    }
    __syncthreads();
    int d = tid & 31, ii = tid >> 5;
    float acc = 0.f;
    #pragma unroll 8
    for (int e = 0; e < 32; ++e) acc += A_s[d][e] * q_s[ii][e];
    const float inv_sqrt = 0.17677669529663687f;
    float v = acc * rel_pri[rh] * inv_sqrt;
    unsigned short hb = f2bf(v);
    float lo = v - bf2f(hb);
    size_t oidx = ((((size_t)b * CR + r) * CH + h) * CN + i0 + ii) * CDK + d;
    Qrhi[oidx] = hb;
    Qrlo[oidx] = f2bf(lo);
}

// ---------------------------------------------------------------------------
// Per (b,j): Kbar = sum_s ty_s*Kt_s (bf16 hi/lo split) and Kty_s = bf16(ty_s*Kt_s),
// all written h-major: [b][h][j][32] / [(b,s)][h][j][32].
__global__ __launch_bounds__(256) void prep_k(const float* __restrict__ Kt,
                                              const float* __restrict__ types,
                                              unsigned short* __restrict__ Kbh,
                                              unsigned short* __restrict__ Kbl,
                                              unsigned short* __restrict__ Kty)
{
    int b = blockIdx.y;
    int j = blockIdx.x * 8 + (threadIdx.x >> 5);
    int c = threadIdx.x & 31;
    int h = c >> 2, d0 = (c & 3) * 8;
    const float* tp = types + ((size_t)b * CN + j) * CT;
    float kb[8];
    #pragma unroll
    for (int k = 0; k < 8; ++k) kb[k] = 0.f;
    #pragma unroll
    for (int s = 0; s < 3; ++s) {
        float ty = tp[s];
        const float* src = Kt + (((size_t)(b * 3 + s)) * CN + j) * COUT + c * 8;
        f32x4 a0 = *(const f32x4*)(src);
        f32x4 a1 = *(const f32x4*)(src + 4);
        u16x8 kt8;
        #pragma unroll
        for (int k = 0; k < 4; ++k) {
            float v0 = ty * a0[k], v1 = ty * a1[k];
            kt8[k] = f2bf(v0); kt8[4 + k] = f2bf(v1);
            kb[k] += v0; kb[4 + k] += v1;
        }
        *(u16x8*)(Kty + (((size_t)(b * 3 + s) * CH + h) * CN + j) * CDK + d0) = kt8;
    }
    u16x8 hv, lv;
    #pragma unroll
    for (int k = 0; k < 8; ++k) {
        unsigned short hb = f2bf(kb[k]);
        hv[k] = hb; lv[k] = f2bf(kb[k] - bf2f(hb));
    }
    *(u16x8*)(Kbh + (((size_t)b * CH + h) * CN + j) * CDK + d0) = hv;
    *(u16x8*)(Kbl + (((size_t)b * CH + h) * CN + j) * CDK + d0) = lv;
}

// ---------------------------------------------------------------------------
// VT[(b,s)][h][e][j] = Vt[b,s,j,h*32+e]  (f16, j contiguous)
__global__ __launch_bounds__(256) void vT_kernel(const float* __restrict__ Vt,
                                                 _Float16* __restrict__ VT)
{
    int j0 = blockIdx.x * 64; int h = blockIdx.y; int bs = blockIdx.z;
    __shared__ float tile[32][72];
    int t = threadIdx.x;
    int jj = t >> 2, e8 = (t & 3) * 8;
    const float* src = Vt + ((size_t)bs * CN + j0 + jj) * COUT + h * CDK + e8;
    f32x4 v0 = *(const f32x4*)(src);
    f32x4 v1 = *(const f32x4*)(src + 4);
    #pragma unroll
    for (int k = 0; k < 4; ++k) { tile[e8 + k][jj] = v0[k]; tile[e8 + 4 + k][jj] = v1[k]; }
    __syncthreads();
    int e = t >> 3, jr = (t & 7) * 8;
    f16x8 o;
    #pragma unroll
    for (int k = 0; k < 8; ++k) o[k] = (_Float16)tile[e][jr + k];
    *(f16x8*)(VT + (((size_t)bs * CH + h) * CDK + e) * CN + j0 + jr) = o;
}

// ---------------------------------------------------------------------------
// MT[r,h,e,e'] = rel_msg[r,h,e',e]  (f16)
__global__ void mT_kernel(const float* __restrict__ rel_msg, _Float16* __restrict__ MT)
{
    int rh = blockIdx.x; int t = threadIdx.x;
    int e = t >> 3, ep4 = (t & 7) * 4;
    f16x4 o;
    #pragma unroll
    for (int k = 0; k < 4; ++k)
        o[k] = (_Float16)rel_msg[((size_t)rh * 32 + ep4 + k) * 32 + e];
    *(f16x4*)(MT + ((size_t)rh * 32 + e) * 32 + ep4) = o;
}

// ---------------------------------------------------------------------------
// coefT[b][j][i][r] = adj[b,i,j] * erel[b,i,j,r]
__global__ __launch_bounds__(256) void coef_t(const float* __restrict__ adj,
                                              const float* __restrict__ erel,
                                              float* __restrict__ coefT)
{
    int b = blockIdx.z; int i0 = blockIdx.y * 32; int j0 = blockIdx.x * 32;
    __shared__ float tile[32][132];
    int t = threadIdx.x;
    {
        int ii = t >> 3, jc = t & 7;
        size_t arow = ((size_t)b * CN + i0 + ii) * CN + j0;
        f32x4 av = *(const f32x4*)(adj + arow + jc * 4);
        #pragma unroll
        for (int kk = 0; kk < 4; ++kk) {
            int j = jc * 4 + kk;
            f32x4 ev = *(const f32x4*)(erel + (arow + j) * 4);
            float a = av[kk];
            f32x4 cv;
            cv[0] = ev[0] * a; cv[1] = ev[1] * a; cv[2] = ev[2] * a; cv[3] = ev[3] * a;
            *(f32x4*)&tile[j][ii * 4] = cv;
        }
    }
    __syncthreads();
    {
        int jj = t >> 3, ic = t & 7;
        size_t orow = ((size_t)b * CN + j0 + jj) * CN + i0;
        #pragma unroll
        for (int kk = 0; kk < 4; ++kk)
            *(f32x4*)(coefT + (orow + ic * 4 + kk) * 4) = *(const f32x4*)&tile[jj][(ic * 4 + kk) * 4];
    }
}

// ---------------------------------------------------------------------------
// MFMA flash attention v3 (unchanged from round 3).
__global__ __launch_bounds__(256, 3) void attn3_kernel(
    const unsigned short* __restrict__ Qrhi, const unsigned short* __restrict__ Qrlo,
    const unsigned short* __restrict__ Kbh,  const unsigned short* __restrict__ Kbl,
    const unsigned short* __restrict__ Kty,
    const _Float16* __restrict__ VT,
    const float* __restrict__ coefT,
    float* __restrict__ Upart,   // [b][h][itile16][part][8][256]
    float* __restrict__ lbuf,    // [part][b][h][i]
    float* __restrict__ rowsum)  // [b][i]
{
    const int h = blockIdx.y;
    const int z = blockIdx.z; const int b = z >> 1, part = z & 1;
    const int tid = threadIdx.x;
    const int wave = tid >> 6, lane = tid & 63;
    const int col = lane & 15, quad = lane >> 4;
    const int i = blockIdx.x * 64 + wave * 16 + col;
    const int jbase = part * 512;

    __shared__ _Float16 vs[2][3][32][20];

    s16x8 qh[4], ql[4];
    #pragma unroll
    for (int r = 0; r < 4; ++r) {
        size_t off = ((((size_t)b * CR + r) * CH + h) * CN + i) * CDK + quad * 8;
        qh[r] = *(const s16x8*)(Qrhi + off);
        ql[r] = *(const s16x8*)(Qrlo + off);
    }

    const int e_st = tid >> 3, jc_st = tid & 7;
    size_t vtb[3];
    #pragma unroll
    for (int s = 0; s < 3; ++s)
        vtb[s] = (((size_t)(b * 3 + s) * CH + h) * CDK + e_st) * CN + jc_st * 2;

    #pragma unroll
    for (int s = 0; s < 3; ++s)
        *(unsigned*)&vs[0][s][e_st][jc_st * 2] = *(const unsigned*)(VT + vtb[s] + jbase);
    __syncthreads();

    f32x4 U[4][2];
    #pragma unroll
    for (int r = 0; r < 4; ++r) { U[r][0] = (f32x4){0.f,0.f,0.f,0.f}; U[r][1] = (f32x4){0.f,0.f,0.f,0.f}; }
    float lpart = 0.f, rspart = 0.f;

    const size_t kbbase = (((size_t)b * CH + h) * CN + col) * CDK + quad * 8;
    size_t ktbase[3];
    #pragma unroll
    for (int s = 0; s < 3; ++s)
        ktbase[s] = (((size_t)(b * 3 + s) * CH + h) * CN + col) * CDK + quad * 8;

    #pragma unroll 1
    for (int js = 0; js < 32; ++js) {
        const int j0 = jbase + js * 16;
        const int buf = js & 1;
        const int jn = jbase + ((js + 1 < 32) ? (js + 1) * 16 : js * 16);
        unsigned pf0 = *(const unsigned*)(VT + vtb[0] + jn);
        unsigned pf1 = *(const unsigned*)(VT + vtb[1] + jn);
        unsigned pf2 = *(const unsigned*)(VT + vtb[2] + jn);

        s16x8 kbh_ = *(const s16x8*)(Kbh + kbbase + (size_t)j0 * CDK);
        s16x8 kbl_ = *(const s16x8*)(Kbl + kbbase + (size_t)j0 * CDK);
        s16x8 kt[3];
        #pragma unroll
        for (int s = 0; s < 3; ++s)
            kt[s] = *(const s16x8*)(Kty + ktbase[s] + (size_t)j0 * CDK);
        f32x4 cf[4];
        #pragma unroll
        for (int reg = 0; reg < 4; ++reg)
            cf[reg] = *(const f32x4*)(coefT + (((size_t)b * CN + j0 + quad * 4 + reg) * CN + i) * 4);

        f32x4 Db[4];
        #pragma unroll
        for (int r = 0; r < 4; ++r) {
            f32x4 d = {0.f, 0.f, 0.f, 0.f};
            d = __builtin_amdgcn_mfma_f32_16x16x32_bf16(kbl_, qh[r], d, 0, 0, 0);
            d = __builtin_amdgcn_mfma_f32_16x16x32_bf16(kbh_, ql[r], d, 0, 0, 0);
            d = __builtin_amdgcn_mfma_f32_16x16x32_bf16(kbh_, qh[r], d, 0, 0, 0);
            Db[r] = d;
        }
        float P[4];
        #pragma unroll
        for (int reg = 0; reg < 4; ++reg) {
            float L = cf[reg][0] * Db[0][reg] + cf[reg][1] * Db[1][reg]
                    + cf[reg][2] * Db[2][reg] + cf[reg][3] * Db[3][reg];
            rspart += L;
            P[reg] = __expf(L);
            lpart += P[reg];
        }
        #pragma unroll
        for (int s = 0; s < 3; ++s) {
            f32x4 Dp[4];
            #pragma unroll
            for (int r = 0; r < 4; ++r) {
                f32x4 d = {0.f, 0.f, 0.f, 0.f};
                Dp[r] = __builtin_amdgcn_mfma_f32_16x16x32_bf16(kt[s], qh[r], d, 0, 0, 0);
            }
            f16x4 v0 = *(const f16x4*)&vs[buf][s][col][quad * 4];
            f16x4 v1 = *(const f16x4*)&vs[buf][s][col + 16][quad * 4];
            #pragma unroll
            for (int r = 0; r < 4; ++r) {
                f16x4 w;
                w[0] = (_Float16)(P[0] * cf[0][r] * Dp[r][0]);
                w[1] = (_Float16)(P[1] * cf[1][r] * Dp[r][1]);
                w[2] = (_Float16)(P[2] * cf[2][r] * Dp[r][2]);
                w[3] = (_Float16)(P[3] * cf[3][r] * Dp[r][3]);
                U[r][0] = __builtin_amdgcn_mfma_f32_16x16x16f16(v0, w, U[r][0], 0, 0, 0);
                U[r][1] = __builtin_amdgcn_mfma_f32_16x16x16f16(v1, w, U[r][1], 0, 0, 0);
            }
        }
        *(unsigned*)&vs[buf ^ 1][0][e_st][jc_st * 2] = pf0;
        *(unsigned*)&vs[buf ^ 1][1][e_st][jc_st * 2] = pf1;
        *(unsigned*)&vs[buf ^ 1][2][e_st][jc_st * 2] = pf2;
        __syncthreads();
    }

    float l = lpart;  l += __shfl_xor(l, 16);  l += __shfl_xor(l, 32);
    float rv = rspart; rv += __shfl_xor(rv, 16); rv += __shfl_xor(rv, 32);
    if (quad == 0) {
        lbuf[(((size_t)part * CB + b) * CH + h) * CN + i] = l;
        atomicAdd(rowsum + (size_t)b * CN + i, rv);
    }
    int itile = blockIdx.x * 4 + wave;
    size_t ub = ((((size_t)(b * CH + h) * 64 + itile) * 2 + part)) * 2048;
    #pragma unroll
    for (int r = 0; r < 4; ++r)
        #pragma unroll
        for (int eh = 0; eh < 2; ++eh)
            *(f32x4*)(Upart + ub + (size_t)(r * 2 + eh) * 256 + lane * 4) = U[r][eh];
}

// ---------------------------------------------------------------------------
// Merge j-split partials, normalize, rel_msg via MFMA, then fused gate + gelu
// + bf16 hi/lo split (output feeds the mode1 MFMA GEMM directly).
__global__ __launch_bounds__(256) void merge_gelu(
    const float* __restrict__ Upart, const float* __restrict__ lbuf,
    const _Float16* __restrict__ MT, const float* __restrict__ rowsum,
    unsigned short* __restrict__ Gh, unsigned short* __restrict__ Gl)
{
    const int h = blockIdx.y, b = blockIdx.z;
    const int tid = threadIdx.x;
    const int wave = tid >> 6, lane = tid & 63;
    const int col = lane & 15, quad = lane >> 4;
    const int itile = blockIdx.x * 4 + wave;
    const int i = itile * 16 + col;

    size_t ub = ((size_t)(b * CH + h) * 64 + itile) * 2 * 2048;
    f32x4 U[4][2];
    #pragma unroll
    for (int r = 0; r < 4; ++r)
        #pragma unroll
        for (int eh = 0; eh < 2; ++eh) {
            f32x4 a = *(const f32x4*)(Upart + ub + (size_t)(r * 2 + eh) * 256 + lane * 4);
            f32x4 c = *(const f32x4*)(Upart + ub + 2048 + (size_t)(r * 2 + eh) * 256 + lane * 4);
            U[r][eh] = a + c;
        }
    float l = lbuf[(((size_t)0 * CB + b) * CH + h) * CN + i]
            + lbuf[(((size_t)1 * CB + b) * CH + h) * CN + i];
    float il = 1.f / l;
    f16x4 Uh[4][2];
    #pragma unroll
    for (int r = 0; r < 4; ++r)
        #pragma unroll
        for (int eh = 0; eh < 2; ++eh) {
            Uh[r][eh][0] = (_Float16)(U[r][eh][0] * il);
            Uh[r][eh][1] = (_Float16)(U[r][eh][1] * il);
            Uh[r][eh][2] = (_Float16)(U[r][eh][2] * il);
            Uh[r][eh][3] = (_Float16)(U[r][eh][3] * il);
        }
    float rsv = rowsum[(size_t)b * CN + i];
    bool gate = rsv > 1e-6f;
    const float is2 = 0.70710678118654752f;
    #pragma unroll
    for (int eo = 0; eo < 2; ++eo) {
        f32x4 acc = {0.f, 0.f, 0.f, 0.f};
        #pragma unroll
        for (int r = 0; r < 4; ++r)
            #pragma unroll
            for (int ep = 0; ep < 2; ++ep) {
                f16x4 mt = *(const f16x4*)(MT + ((size_t)(r * 8 + h) * 32 + eo * 16 + col) * 32
                                               + ep * 16 + quad * 4);
                acc = __builtin_amdgcn_mfma_f32_16x16x16f16(mt, Uh[r][ep], acc, 0, 0, 0);
            }
        u16x4 hv, lv;
        #pragma unroll
        for (int k = 0; k < 4; ++k) {
            float x = gate ? acc[k] : 0.f;
            float g = 0.5f * x * (1.f + erff(x * is2));
            unsigned short hb = f2bf(g);
            hv[k] = hb; lv[k] = f2bf(g - bf2f(hb));
        }
        size_t off = ((size_t)b * CN + i) * COUT + h * CDK + eo * 16 + quad * 4;
        *(u16x4*)(Gh + off) = hv;
        *(u16x4*)(Gl + off) = lv;
    }
}

// ---------------------------------------------------------------------------
// gated residual + layernorm + soft-type mix; one wave per (b,i) row, no barriers.
__global__ __launch_bounds__(256) void final_ln2(
    const float* __restrict__ trans, const float* __restrict__ x,
    const float* __restrict__ types, const float* __restrict__ skip,
    const float* __restrict__ gamma, const float* __restrict__ beta,
    float* __restrict__ out)
{
    int wave = threadIdx.x >> 6, lane = threadIdx.x & 63;
    int bi = blockIdx.x * 4 + wave;
    int b = bi >> 10, i = bi & 1023;
    f32x4 xo = *(const f32x4*)(x + (size_t)bi * COUT + lane * 4);
    f32x4 accum = {0.f, 0.f, 0.f, 0.f};
    const float* tp = types + (size_t)bi * CT;
    #pragma unroll 1
    for (int t = 0; t < CT; ++t) {
        float al = 1.f / (1.f + __expf(-skip[t]));
        f32x4 tr = *(const f32x4*)(trans + (((size_t)b * CT + t) * CN + i) * COUT + lane * 4);
        f32x4 res;
        float s = 0.f;
        #pragma unroll
        for (int k = 0; k < 4; ++k) { res[k] = tr[k] * al + xo[k] * (1.f - al); s += res[k]; }
        #pragma unroll
        for (int mk = 1; mk < 64; mk <<= 1) s += __shfl_xor(s, mk);
        float mu = s * (1.f / COUT);
        f32x4 dc; float s2 = 0.f;
        #pragma unroll
        for (int k = 0; k < 4; ++k) { dc[k] = res[k] - mu; s2 += dc[k] * dc[k]; }
        #pragma unroll
        for (int mk = 1; mk < 64; mk <<= 1) s2 += __shfl_xor(s2, mk);
        float inv = rsqrtf(s2 * (1.f / COUT) + 1e-5f);
        f32x4 g = *(const f32x4*)(gamma + (size_t)t * COUT + lane * 4);
        f32x4 be = *(const f32x4*)(beta + (size_t)t * COUT + lane * 4);
        float ty = tp[t];
        #pragma unroll
        for (int k = 0; k < 4; ++k) accum[k] += ty * (dc[k] * inv * g[k] + be[k]);
    }
    *(f32x4*)(out + (size_t)bi * COUT + lane * 4) = accum;
}

// ---------------------------------------------------------------------------
extern "C" void kernel_launch(void* const* d_in, const int* in_sizes, int n_in,
                              void* d_out, int out_size, void* d_ws, size_t ws_size,
                              hipStream_t stream)
{
    (void)in_sizes; (void)n_in; (void)out_size; (void)ws_size;
    const float* nf      = (const float*)d_in[0];
    const float* types   = (const float*)d_in[1];
    const float* adj     = (const float*)d_in[2];
    const float* erel    = (const float*)d_in[3];
    const float* Wq      = (const float*)d_in[4];
    const float* bq      = (const float*)d_in[5];
    const float* Wk      = (const float*)d_in[6];
    const float* bk      = (const float*)d_in[7];
    const float* Wv      = (const float*)d_in[8];
    const float* bv      = (const float*)d_in[9];
    const float* Wa      = (const float*)d_in[10];
    const float* ba      = (const float*)d_in[11];
    const float* rel_pri = (const float*)d_in[12];
    const float* rel_att = (const float*)d_in[13];
    const float* rel_msg = (const float*)d_in[14];
    const float* skip    = (const float*)d_in[15];
    const float* gamma   = (const float*)d_in[16];
    const float* beta    = (const float*)d_in[17];
    float* out = (float*)d_out;

    float* ws = (float*)d_ws;
    size_t o = 0;
    float* pool0 = ws + o; o += 3 * (size_t)CB * CT * CN * COUT;   // 9.44M f32
    float* Qt  = pool0;
    float* Ktb = pool0 + (size_t)CB * CT * CN * COUT;
    float* Vtb = pool0 + 2 * (size_t)CB * CT * CN * COUT;
    float* Qbar = ws + o; o += (size_t)CB * CN * COUT;
    float* rsb  = ws + o; o += (size_t)CB * CN;
    float* lbufp = ws + o; o += 2 * (size_t)CB * CH * CN;
    unsigned short* Qrhi = (unsigned short*)(ws + o); o += (size_t)CB * CR * CN * COUT / 2;
    unsigned short* Qrlo = (unsigned short*)(ws + o); o += (size_t)CB * CR * CN * COUT / 2;
    unsigned short* Kbh  = (unsigned short*)(ws + o); o += (size_t)CB * CH * CN * CDK / 2;
    unsigned short* Kbl  = (unsigned short*)(ws + o); o += (size_t)CB * CH * CN * CDK / 2;
    unsigned short* Kty  = (unsigned short*)(ws + o); o += (size_t)CB * CT * CH * CN * CDK / 2;
    _Float16* VTb = (_Float16*)(ws + o);              o += (size_t)CB * CT * CH * CDK * CN / 2;
    _Float16* MTb = (_Float16*)(ws + o);              o += (size_t)CR * CH * CDK * CDK / 2;
    unsigned short* Xh = (unsigned short*)(ws + o);   o += (size_t)CB * CN * COUT / 2;
    unsigned short* Xl = (unsigned short*)(ws + o);   o += (size_t)CB * CN * COUT / 2;
    unsigned short* Gh = (unsigned short*)(ws + o);   o += (size_t)CB * CN * COUT / 2;
    unsigned short* Gl = (unsigned short*)(ws + o);   o += (size_t)CB * CN * COUT / 2;
    unsigned short* WTh = (unsigned short*)(ws + o);  o += (size_t)12 * COUT * COUT / 2;
    unsigned short* WTl = (unsigned short*)(ws + o);  o += (size_t)12 * COUT * COUT / 2;
    float* coefT = ws + o; o += (size_t)CB * CN * CN * CR;   // 16.8M f32
    // overlays on pool0 (Qt/Ktb/Vtb all dead by attn3)
    float* Upart  = pool0;                               // 8.39M f32
    float* transb = pool0 + 3 * (size_t)CB * CN * COUT;  // after attn (Vtb region dead post-vT? use end)

    zero_rs<<<CB * CN / 256, 256, 0, stream>>>(rsb);
    splitx<<<CB * CN * COUT / 4 / 256, 256, 0, stream>>>(nf, Xh, Xl);
    wsplit<<<dim3(8, 8, 12), 256, 0, stream>>>(Wq, Wk, Wv, Wa, WTh, WTl);
    mfma_gemm<<<dim3(8, 2, CB * 9), 256, 0, stream>>>(0, Xh, Xl, WTh, WTl,
                                                      bq, bk, bv, ba, Qt, Ktb, Vtb);
    coef_t<<<dim3(32, 32, CB), 256, 0, stream>>>(adj, erel, coefT);
    mix_qbar<<<CB * CN * COUT / 4 / 256, 256, 0, stream>>>(Qt, types, Qbar);
    qr3_kernel<<<dim3(CN / 8, CR * CH, CB), 256, 0, stream>>>(Qbar, rel_att, rel_pri, Qrhi, Qrlo);
    prep_k<<<dim3(CN / 8, CB), 256, 0, stream>>>(Ktb, types, Kbh, Kbl, Kty);
    vT_kernel<<<dim3(CN / 64, CH, CB * CT), 256, 0, stream>>>(Vtb, VTb);
    mT_kernel<<<CR * CH, 256, 0, stream>>>(rel_msg, MTb);
    attn3_kernel<<<dim3(16, CH, CB * 2), 256, 0, stream>>>(Qrhi, Qrlo, Kbh, Kbl, Kty, VTb, coefT,
                                                           Upart, lbufp, rsb);
    merge_gelu<<<dim3(16, CH, CB), 256, 0, stream>>>(Upart, lbufp, MTb, rsb, Gh, Gl);
    mfma_gemm<<<dim3(8, 2, CB * CT), 256, 0, stream>>>(1, Gh, Gl, WTh, WTl,
                                                       bq, bk, bv, ba, transb, transb, transb);
    final_ln2<<<CB * CN / 4, 256, 0, stream>>>(transb, nf, types, skip, gamma, beta, out);
}

// Round 6
// 374.720 us; speedup vs baseline: 5.4656x; 1.0223x over previous
//
#include <hip/hip_runtime.h>
#include <math.h>

// Problem constants
constexpr int CB = 4, CN = 1024, CT = 3, CR = 4, CH = 8, CDK = 32, COUT = 256;

typedef __attribute__((ext_vector_type(4))) float f32x4;
typedef __attribute__((ext_vector_type(8))) short s16x8;
typedef __attribute__((ext_vector_type(2))) _Float16 f16x2;
typedef __attribute__((ext_vector_type(4))) _Float16 f16x4;
typedef __attribute__((ext_vector_type(8))) _Float16 f16x8;
typedef __attribute__((ext_vector_type(4))) unsigned short u16x4;
typedef __attribute__((ext_vector_type(8))) unsigned short u16x8;

union W4 { f16x4 v4; f16x2 v2[2]; };

__device__ inline unsigned short f2bf(float x) {
    unsigned u = __float_as_uint(x);
    unsigned r = (u + 0x7fffu + ((u >> 16) & 1u)) >> 16;
    return (unsigned short)r;
}
__device__ inline float bf2f(unsigned short b) {
    return __uint_as_float(((unsigned)b) << 16);
}
__device__ inline f16x2 pk2(float a, float b) {
    auto t = __builtin_amdgcn_cvt_pkrtz(a, b);   // __fp16 ext_vector(2)
    f16x2 r;
    __builtin_memcpy(&r, &t, sizeof(r));
    return r;
}

// ---------------------------------------------------------------------------
// Fused independent prep work, partitioned by blockIdx.x:
// [0,1024)    splitx: nf -> bf16 hi/lo
// [1024,1792) wsplit: weight transpose + split (12 weight mats, 64 tiles each)
// [1792,1824) mT: rel_msg transpose to f16
// [1824,1840) zero rowsum
// [1840,5936) coef_t: coefT[b][j][i][r] = adj[b,i,j]*erel[b,i,j,r]
__global__ __launch_bounds__(256) void prep0(
    const float* __restrict__ nf,
    unsigned short* __restrict__ Xh, unsigned short* __restrict__ Xl,
    const float* __restrict__ Wq, const float* __restrict__ Wk,
    const float* __restrict__ Wv, const float* __restrict__ Wa,
    unsigned short* __restrict__ WTh, unsigned short* __restrict__ WTl,
    const float* __restrict__ rel_msg, _Float16* __restrict__ MT,
    float* __restrict__ rs,
    const float* __restrict__ adj, const float* __restrict__ erel,
    float* __restrict__ coefT)
{
    __shared__ float smem[32 * 132];
    const int bx = blockIdx.x, tid = threadIdx.x;
    if (bx < 1024) {
        size_t idx = ((size_t)bx * 256 + tid) * 4;
        f32x4 v = *(const f32x4*)(nf + idx);
        u16x4 hv, lv;
        #pragma unroll
        for (int k = 0; k < 4; ++k) {
            unsigned short hb = f2bf(v[k]);
            hv[k] = hb; lv[k] = f2bf(v[k] - bf2f(hb));
        }
        *(u16x4*)(Xh + idx) = hv;
        *(u16x4*)(Xl + idx) = lv;
    } else if (bx < 1792) {
        int w = bx - 1024;
        int zz = w >> 6; int rem = w & 63;
        int k0 = (rem >> 3) * 32, n0 = (rem & 7) * 32;
        int t = zz % 3;
        const float* W;
        if (zz < 9) { int w3 = zz / 3; W = (w3 == 0 ? Wq : (w3 == 1 ? Wk : Wv)); }
        else W = Wa;
        W += (size_t)t * COUT * COUT;
        {
            int k = tid >> 3, n4 = (tid & 7) * 4;
            f32x4 v = *(const f32x4*)(W + (size_t)(k0 + k) * COUT + n0 + n4);
            smem[(n4 + 0) * 33 + k] = v[0]; smem[(n4 + 1) * 33 + k] = v[1];
            smem[(n4 + 2) * 33 + k] = v[2]; smem[(n4 + 3) * 33 + k] = v[3];
        }
        __syncthreads();
        int n = tid >> 3, k4 = (tid & 7) * 4;
        u16x4 hv, lv;
        #pragma unroll
        for (int j = 0; j < 4; ++j) {
            float x = smem[n * 33 + k4 + j];
            unsigned short hb = f2bf(x);
            hv[j] = hb; lv[j] = f2bf(x - bf2f(hb));
        }
        size_t off = (size_t)zz * COUT * COUT + (size_t)(n0 + n) * COUT + k0 + k4;
        *(u16x4*)(WTh + off) = hv;
        *(u16x4*)(WTl + off) = lv;
    } else if (bx < 1824) {
        int rh = bx - 1792;
        int e = tid >> 3, ep4 = (tid & 7) * 4;
        f16x4 o;
        #pragma unroll
        for (int k = 0; k < 4; ++k)
            o[k] = (_Float16)rel_msg[((size_t)rh * 32 + ep4 + k) * 32 + e];
        *(f16x4*)(MT + ((size_t)rh * 32 + e) * 32 + ep4) = o;
    } else if (bx < 1840) {
        rs[(bx - 1824) * 256 + tid] = 0.f;
    } else {
        int c = bx - 1840;
        int b = c >> 10; int rem = c & 1023;
        int i0 = (rem >> 5) * 32; int j0 = (rem & 31) * 32;
        {
            int ii = tid >> 3, jc = tid & 7;
            size_t arow = ((size_t)b * CN + i0 + ii) * CN + j0;
            f32x4 av = *(const f32x4*)(adj + arow + jc * 4);
            #pragma unroll
            for (int kk = 0; kk < 4; ++kk) {
                int j = jc * 4 + kk;
                f32x4 ev = *(const f32x4*)(erel + (arow + j) * 4);
                float a = av[kk];
                f32x4 cv;
                cv[0] = ev[0] * a; cv[1] = ev[1] * a; cv[2] = ev[2] * a; cv[3] = ev[3] * a;
                *(f32x4*)&smem[j * 132 + ii * 4] = cv;
            }
        }
        __syncthreads();
        {
            int jj = tid >> 3, ic = tid & 7;
            size_t orow = ((size_t)b * CN + j0 + jj) * CN + i0;
            #pragma unroll
            for (int kk = 0; kk < 4; ++kk)
                *(f32x4*)(coefT + (orow + ic * 4 + kk) * 4) =
                    *(const f32x4*)&smem[jj * 132 + (ic * 4 + kk) * 4];
        }
    }
}

// ---------------------------------------------------------------------------
// bf16-split MFMA GEMM: Y[1024,256] = X[1024,256] @ W[256,256] + bias.
__global__ __launch_bounds__(256) void mfma_gemm(
    int mode,
    const unsigned short* __restrict__ Ah, const unsigned short* __restrict__ Al,
    const unsigned short* __restrict__ WTh, const unsigned short* __restrict__ WTl,
    const float* __restrict__ bq, const float* __restrict__ bk,
    const float* __restrict__ bv, const float* __restrict__ ba,
    float* __restrict__ Y0, float* __restrict__ Y1, float* __restrict__ Y2)
{
    int z = blockIdx.z;
    int b, t, widx;
    const float* bias;
    float* Y;
    if (mode == 0) {
        b = z / 9; int r9 = z % 9; int w3 = r9 / 3; t = r9 % 3;
        widx = w3 * 3 + t;
        bias = (w3 == 0 ? bq : (w3 == 1 ? bk : bv)) + t * COUT;
        Y = (w3 == 0 ? Y0 : (w3 == 1 ? Y1 : Y2)) + ((size_t)b * CT + t) * CN * COUT;
    } else {
        b = z / CT; t = z % CT;
        widx = 9 + t;
        bias = ba + t * COUT;
        Y = Y0 + ((size_t)b * CT + t) * CN * COUT;
    }
    const unsigned short* Ahb = Ah + (size_t)b * CN * COUT;
    const unsigned short* Alb = Al + (size_t)b * CN * COUT;
    const unsigned short* Bhb = WTh + (size_t)widx * COUT * COUT;
    const unsigned short* Blb = WTl + (size_t)widx * COUT * COUT;

    const int M0 = blockIdx.x * 128, N0 = blockIdx.y * 128;
    __shared__ unsigned short As[2][128][40];
    __shared__ unsigned short Bs[2][128][40];
    const int tid = threadIdx.x;
    const int wave = tid >> 6, lane = tid & 63;
    const int wm = wave & 1, wn = wave >> 1;
    const int col = lane & 15, quad = lane >> 4;

    f32x4 acc[4][4];
    #pragma unroll
    for (int mt = 0; mt < 4; ++mt)
        #pragma unroll
        for (int nt = 0; nt < 4; ++nt) acc[mt][nt] = (f32x4){0.f, 0.f, 0.f, 0.f};

    for (int kt = 0; kt < COUT; kt += 32) {
        #pragma unroll
        for (int q = 0; q < 2; ++q) {
            int f = q * 256 + tid;
            int m = f >> 2, kc = (f & 3) * 8;
            *(u16x8*)&As[0][m][kc] = *(const u16x8*)(Ahb + (size_t)(M0 + m) * COUT + kt + kc);
            *(u16x8*)&As[1][m][kc] = *(const u16x8*)(Alb + (size_t)(M0 + m) * COUT + kt + kc);
            *(u16x8*)&Bs[0][m][kc] = *(const u16x8*)(Bhb + (size_t)(N0 + m) * COUT + kt + kc);
            *(u16x8*)&Bs[1][m][kc] = *(const u16x8*)(Blb + (size_t)(N0 + m) * COUT + kt + kc);
        }
        __syncthreads();
        s16x8 ah[4], al4[4], bh[4], bl4[4];
        #pragma unroll
        for (int mt = 0; mt < 4; ++mt) {
            ah[mt]  = *(const s16x8*)&As[0][wm * 64 + mt * 16 + col][quad * 8];
            al4[mt] = *(const s16x8*)&As[1][wm * 64 + mt * 16 + col][quad * 8];
        }
        #pragma unroll
        for (int nt = 0; nt < 4; ++nt) {
            bh[nt]  = *(const s16x8*)&Bs[0][wn * 64 + nt * 16 + col][quad * 8];
            bl4[nt] = *(const s16x8*)&Bs[1][wn * 64 + nt * 16 + col][quad * 8];
        }
        #pragma unroll
        for (int mt = 0; mt < 4; ++mt)
            #pragma unroll
            for (int nt = 0; nt < 4; ++nt) {
                acc[mt][nt] = __builtin_amdgcn_mfma_f32_16x16x32_bf16(al4[mt], bh[nt], acc[mt][nt], 0, 0, 0);
                acc[mt][nt] = __builtin_amdgcn_mfma_f32_16x16x32_bf16(ah[mt], bl4[nt], acc[mt][nt], 0, 0, 0);
                acc[mt][nt] = __builtin_amdgcn_mfma_f32_16x16x32_bf16(ah[mt], bh[nt], acc[mt][nt], 0, 0, 0);
            }
        __syncthreads();
    }
    float bb[4];
    #pragma unroll
    for (int nt = 0; nt < 4; ++nt) bb[nt] = bias[N0 + wn * 64 + nt * 16 + col];
    #pragma unroll
    for (int mt = 0; mt < 4; ++mt)
        #pragma unroll
        for (int nt = 0; nt < 4; ++nt) {
            int n = N0 + wn * 64 + nt * 16 + col;
            #pragma unroll
            for (int reg = 0; reg < 4; ++reg) {
                int m = M0 + wm * 64 + mt * 16 + quad * 4 + reg;
                Y[(size_t)m * COUT + n] = acc[mt][nt][reg] + bb[nt];
            }
        }
}

// ---------------------------------------------------------------------------
// Qbar[b,i,:] = sum_t types[b,i,t] * Qt[b,t,i,:]
__global__ void mix_qbar(const float* __restrict__ Qt, const float* __restrict__ types,
                         float* __restrict__ Qbar)
{
    int idx = blockIdx.x * 256 + threadIdx.x;
    int bi = idx >> 6;
    int o4 = (idx & 63) * 4;
    int b = bi >> 10;
    const float* tp = types + (size_t)bi * CT;
    float t0 = tp[0], t1 = tp[1], t2 = tp[2];
    size_t nbase = ((size_t)b * CT) * CN * COUT + (size_t)(bi & 1023) * COUT + o4;
    float4 q0 = *(const float4*)(Qt + nbase);
    float4 q1 = *(const float4*)(Qt + nbase + (size_t)CN * COUT);
    float4 q2 = *(const float4*)(Qt + nbase + 2 * (size_t)CN * COUT);
    float4 o;
    o.x = t0 * q0.x + t1 * q1.x + t2 * q2.x;
    o.y = t0 * q0.y + t1 * q1.y + t2 * q2.y;
    o.z = t0 * q0.z + t1 * q1.z + t2 * q2.z;
    o.w = t0 * q0.w + t1 * q1.w + t2 * q2.w;
    *(float4*)(Qbar + (size_t)bi * COUT + o4) = o;
}

// ---------------------------------------------------------------------------
// Qr[b,r,h,i,d] = (pri[r,h]/sqrt(dk)) * sum_e rel_att[r,h,d,e]*Qbar[b,i,h*32+e]
__global__ __launch_bounds__(256) void qr3_kernel(const float* __restrict__ Qbar,
                                                  const float* __restrict__ rel_att,
                                                  const float* __restrict__ rel_pri,
                                                  unsigned short* __restrict__ Qrhi,
                                                  unsigned short* __restrict__ Qrlo)
{
    int i0 = blockIdx.x * 8;
    int rh = blockIdx.y; int r = rh >> 3, h = rh & 7;
    int b = blockIdx.z;
    __shared__ float A_s[32][33];
    __shared__ float q_s[8][32];
    int tid = threadIdx.x;
    {
        int f = tid * 4; int d = f >> 5, e = f & 31;
        float4 v = *(const float4*)(rel_att + ((size_t)rh * 32 + d) * 32 + e);
        A_s[d][e] = v.x; A_s[d][e + 1] = v.y; A_s[d][e + 2] = v.z; A_s[d][e + 3] = v.w;
        int ii = tid >> 5, ee = tid & 31;
        q_s[ii][ee] = Qbar[((size_t)b * CN + i0 + ii) * COUT + h * CDK + ee];
    }
    __syncthreads();
    int d = tid & 31, ii = tid >> 5;
    float acc = 0.f;
    #pragma unroll 8
    for (int e = 0; e < 32; ++e) acc += A_s[d][e] * q_s[ii][e];
    const float inv_sqrt = 0.17677669529663687f;
    float v = acc * rel_pri[rh] * inv_sqrt;
    unsigned short hb = f2bf(v);
    float lo = v - bf2f(hb);
    size_t oidx = ((((size_t)b * CR + r) * CH + h) * CN + i0 + ii) * CDK + d;
    Qrhi[oidx] = hb;
    Qrlo[oidx] = f2bf(lo);
}

// ---------------------------------------------------------------------------
// Fused K-prep + V-transpose:
// [0,512):    per (b,j): Kbar=sum_s ty_s*Kt_s (split) + Kty_s, h-major
// [512,2048): VT[(b,s)][h][e][j] = Vt[b,s,j,h*32+e] (f16)
__global__ __launch_bounds__(256) void prep_kv(
    const float* __restrict__ Kt, const float* __restrict__ Vt,
    const float* __restrict__ types,
    unsigned short* __restrict__ Kbh, unsigned short* __restrict__ Kbl,
    unsigned short* __restrict__ Kty, _Float16* __restrict__ VT)
{
    __shared__ float tile[32][72];
    const int bx = blockIdx.x, tid = threadIdx.x;
    if (bx < 512) {
        int b = bx >> 7, jt = bx & 127;
        int j = jt * 8 + (tid >> 5);
        int c = tid & 31;
        int h = c >> 2, d0 = (c & 3) * 8;
        const float* tp = types + ((size_t)b * CN + j) * CT;
        float kb[8];
        #pragma unroll
        for (int k = 0; k < 8; ++k) kb[k] = 0.f;
        #pragma unroll
        for (int s = 0; s < 3; ++s) {
            float ty = tp[s];
            const float* src = Kt + (((size_t)(b * 3 + s)) * CN + j) * COUT + c * 8;
            f32x4 a0 = *(const f32x4*)(src);
            f32x4 a1 = *(const f32x4*)(src + 4);
            u16x8 kt8;
            #pragma unroll
            for (int k = 0; k < 4; ++k) {
                float v0 = ty * a0[k], v1 = ty * a1[k];
                kt8[k] = f2bf(v0); kt8[4 + k] = f2bf(v1);
                kb[k] += v0; kb[4 + k] += v1;
            }
            *(u16x8*)(Kty + (((size_t)(b * 3 + s) * CH + h) * CN + j) * CDK + d0) = kt8;
        }
        u16x8 hv, lv;
        #pragma unroll
        for (int k = 0; k < 8; ++k) {
            unsigned short hb = f2bf(kb[k]);
            hv[k] = hb; lv[k] = f2bf(kb[k] - bf2f(hb));
        }
        *(u16x8*)(Kbh + (((size_t)b * CH + h) * CN + j) * CDK + d0) = hv;
        *(u16x8*)(Kbl + (((size_t)b * CH + h) * CN + j) * CDK + d0) = lv;
    } else {
        int idx2 = bx - 512;
        int bs = idx2 >> 7; int rem = idx2 & 127;
        int h = rem >> 4; int j0 = (rem & 15) * 64;
        int jj = tid >> 2, e8 = (tid & 3) * 8;
        const float* src = Vt + ((size_t)bs * CN + j0 + jj) * COUT + h * CDK + e8;
        f32x4 v0 = *(const f32x4*)(src);
        f32x4 v1 = *(const f32x4*)(src + 4);
        #pragma unroll
        for (int k = 0; k < 4; ++k) { tile[e8 + k][jj] = v0[k]; tile[e8 + 4 + k][jj] = v1[k]; }
        __syncthreads();
        int e = tid >> 3, jr = (tid & 7) * 8;
        f16x8 o;
        #pragma unroll
        for (int k = 0; k < 8; ++k) o[k] = (_Float16)tile[e][jr + k];
        *(f16x8*)(VT + (((size_t)bs * CH + h) * CDK + e) * CN + j0 + jr) = o;
    }
}

// ---------------------------------------------------------------------------
// MFMA flash attention v4: software-pipelined K/cf loads (1 iter ahead),
// packed-f16 PV weight computation. Grid (16, H, B*2parts), 4 waves/block.
__global__ __launch_bounds__(256, 3) void attn4_kernel(
    const unsigned short* __restrict__ Qrhi, const unsigned short* __restrict__ Qrlo,
    const unsigned short* __restrict__ Kbh,  const unsigned short* __restrict__ Kbl,
    const unsigned short* __restrict__ Kty,
    const _Float16* __restrict__ VT,
    const float* __restrict__ coefT,
    float* __restrict__ Upart, float* __restrict__ lbuf, float* __restrict__ rowsum)
{
    const int h = blockIdx.y;
    const int z = blockIdx.z; const int b = z >> 1, part = z & 1;
    const int tid = threadIdx.x;
    const int wave = tid >> 6, lane = tid & 63;
    const int col = lane & 15, quad = lane >> 4;
    const int i = blockIdx.x * 64 + wave * 16 + col;
    const int jbase = part * 512;

    __shared__ _Float16 vs[2][3][32][20];

    s16x8 qh[4], ql[4];
    #pragma unroll
    for (int r = 0; r < 4; ++r) {
        size_t off = ((((size_t)b * CR + r) * CH + h) * CN + i) * CDK + quad * 8;
        qh[r] = *(const s16x8*)(Qrhi + off);
        ql[r] = *(const s16x8*)(Qrlo + off);
    }

    const int e_st = tid >> 3, jc_st = tid & 7;
    size_t vtb[3];
    #pragma unroll
    for (int s = 0; s < 3; ++s)
        vtb[s] = (((size_t)(b * 3 + s) * CH + h) * CDK + e_st) * CN + jc_st * 2;

    #pragma unroll
    for (int s = 0; s < 3; ++s)
        *(unsigned*)&vs[0][s][e_st][jc_st * 2] = *(const unsigned*)(VT + vtb[s] + jbase);

    f32x4 U[4][2];
    #pragma unroll
    for (int r = 0; r < 4; ++r) { U[r][0] = (f32x4){0.f,0.f,0.f,0.f}; U[r][1] = (f32x4){0.f,0.f,0.f,0.f}; }
    float lpart = 0.f, rspart = 0.f;

    const size_t kbbase = (((size_t)b * CH + h) * CN + col) * CDK + quad * 8;
    size_t ktbase[3];
    #pragma unroll
    for (int s = 0; s < 3; ++s)
        ktbase[s] = (((size_t)(b * 3 + s) * CH + h) * CN + col) * CDK + quad * 8;
    const size_t cfrow = ((size_t)b * CN + quad * 4) * CN + i;   // + j*CN, *4 for r

    // prologue: prefetch K/cf for js=0
    s16x8 p_bh[2], p_bl[2];
    f32x4 p_cf[2][4];
    {
        const int j0 = jbase;
        p_bh[0] = *(const s16x8*)(Kbh + kbbase + (size_t)j0 * CDK);
        p_bl[0] = *(const s16x8*)(Kbl + kbbase + (size_t)j0 * CDK);
        #pragma unroll
        for (int reg = 0; reg < 4; ++reg)
            p_cf[0][reg] = *(const f32x4*)(coefT + (cfrow + (size_t)(j0 + reg) * CN) * 4);
    }
    __syncthreads();

    #pragma unroll 2
    for (int js = 0; js < 32; ++js) {
        const int cur = js & 1, nx = cur ^ 1;
        const int j0 = jbase + js * 16;
        const int buf = js & 1;
        // current-iter Kty loads FIRST (consumed latest this iter)
        s16x8 kt0 = *(const s16x8*)(Kty + ktbase[0] + (size_t)j0 * CDK);
        s16x8 kt1 = *(const s16x8*)(Kty + ktbase[1] + (size_t)j0 * CDK);
        s16x8 kt2 = *(const s16x8*)(Kty + ktbase[2] + (size_t)j0 * CDK);
        // V prefetch for next tile
        const int jn = jbase + ((js + 1 < 32) ? (js + 1) * 16 : js * 16);
        unsigned pf0 = *(const unsigned*)(VT + vtb[0] + jn);
        unsigned pf1 = *(const unsigned*)(VT + vtb[1] + jn);
        unsigned pf2 = *(const unsigned*)(VT + vtb[2] + jn);
        // K/cf prefetch for next iteration
        p_bh[nx] = *(const s16x8*)(Kbh + kbbase + (size_t)jn * CDK);
        p_bl[nx] = *(const s16x8*)(Kbl + kbbase + (size_t)jn * CDK);
        #pragma unroll
        for (int reg = 0; reg < 4; ++reg)
            p_cf[nx][reg] = *(const f32x4*)(coefT + (cfrow + (size_t)(jn + reg) * CN) * 4);

        // Dbar (precise logits path), inputs prefetched last iteration
        f32x4 Db[4];
        #pragma unroll
        for (int r = 0; r < 4; ++r) {
            f32x4 d = {0.f, 0.f, 0.f, 0.f};
            d = __builtin_amdgcn_mfma_f32_16x16x32_bf16(p_bl[cur], qh[r], d, 0, 0, 0);
            d = __builtin_amdgcn_mfma_f32_16x16x32_bf16(p_bh[cur], ql[r], d, 0, 0, 0);
            d = __builtin_amdgcn_mfma_f32_16x16x32_bf16(p_bh[cur], qh[r], d, 0, 0, 0);
            Db[r] = d;
        }
        float P[4];
        #pragma unroll
        for (int reg = 0; reg < 4; ++reg) {
            float L = p_cf[cur][reg][0] * Db[0][reg] + p_cf[cur][reg][1] * Db[1][reg]
                    + p_cf[cur][reg][2] * Db[2][reg] + p_cf[cur][reg][3] * Db[3][reg];
            rspart += L;
            P[reg] = __expf(L);
            lpart += P[reg];
        }
        // packed P*cf per relation (reused across s)
        f16x2 pA[4], pB[4];
        #pragma unroll
        for (int r = 0; r < 4; ++r) {
            pA[r] = pk2(P[0] * p_cf[cur][0][r], P[1] * p_cf[cur][1][r]);
            pB[r] = pk2(P[2] * p_cf[cur][2][r], P[3] * p_cf[cur][3][r]);
        }
        // per-s score + PV
        #pragma unroll
        for (int s = 0; s < 3; ++s) {
            s16x8 kts = (s == 0) ? kt0 : (s == 1) ? kt1 : kt2;
            f32x4 Dp[4];
            #pragma unroll
            for (int r = 0; r < 4; ++r) {
                f32x4 d = {0.f, 0.f, 0.f, 0.f};
                Dp[r] = __builtin_amdgcn_mfma_f32_16x16x32_bf16(kts, qh[r], d, 0, 0, 0);
            }
            f16x4 v0 = *(const f16x4*)&vs[buf][s][col][quad * 4];
            f16x4 v1 = *(const f16x4*)&vs[buf][s][col + 16][quad * 4];
            #pragma unroll
            for (int r = 0; r < 4; ++r) {
                W4 w;
                w.v2[0] = pA[r] * pk2(Dp[r][0], Dp[r][1]);
                w.v2[1] = pB[r] * pk2(Dp[r][2], Dp[r][3]);
                U[r][0] = __builtin_amdgcn_mfma_f32_16x16x16f16(v0, w.v4, U[r][0], 0, 0, 0);
                U[r][1] = __builtin_amdgcn_mfma_f32_16x16x16f16(v1, w.v4, U[r][1], 0, 0, 0);
            }
        }
        // stage next V tile
        *(unsigned*)&vs[buf ^ 1][0][e_st][jc_st * 2] = pf0;
        *(unsigned*)&vs[buf ^ 1][1][e_st][jc_st * 2] = pf1;
        *(unsigned*)&vs[buf ^ 1][2][e_st][jc_st * 2] = pf2;
        __syncthreads();
    }

    float l = lpart;  l += __shfl_xor(l, 16);  l += __shfl_xor(l, 32);
    float rv = rspart; rv += __shfl_xor(rv, 16); rv += __shfl_xor(rv, 32);
    if (quad == 0) {
        lbuf[(((size_t)part * CB + b) * CH + h) * CN + i] = l;
        atomicAdd(rowsum + (size_t)b * CN + i, rv);
    }
    int itile = blockIdx.x * 4 + wave;
    size_t ub = ((((size_t)(b * CH + h) * 64 + itile) * 2 + part)) * 2048;
    #pragma unroll
    for (int r = 0; r < 4; ++r)
        #pragma unroll
        for (int eh = 0; eh < 2; ++eh)
            *(f32x4*)(Upart + ub + (size_t)(r * 2 + eh) * 256 + lane * 4) = U[r][eh];
}

// ---------------------------------------------------------------------------
// Merge j-split partials, normalize, rel_msg via MFMA, gate + gelu + split.
__global__ __launch_bounds__(256) void merge_gelu(
    const float* __restrict__ Upart, const float* __restrict__ lbuf,
    const _Float16* __restrict__ MT, const float* __restrict__ rowsum,
    unsigned short* __restrict__ Gh, unsigned short* __restrict__ Gl)
{
    const int h = blockIdx.y, b = blockIdx.z;
    const int tid = threadIdx.x;
    const int wave = tid >> 6, lane = tid & 63;
    const int col = lane & 15, quad = lane >> 4;
    const int itile = blockIdx.x * 4 + wave;
    const int i = itile * 16 + col;

    size_t ub = ((size_t)(b * CH + h) * 64 + itile) * 2 * 2048;
    f32x4 U[4][2];
    #pragma unroll
    for (int r = 0; r < 4; ++r)
        #pragma unroll
        for (int eh = 0; eh < 2; ++eh) {
            f32x4 a = *(const f32x4*)(Upart + ub + (size_t)(r * 2 + eh) * 256 + lane * 4);
            f32x4 c = *(const f32x4*)(Upart + ub + 2048 + (size_t)(r * 2 + eh) * 256 + lane * 4);
            U[r][eh] = a + c;
        }
    float l = lbuf[(((size_t)0 * CB + b) * CH + h) * CN + i]
            + lbuf[(((size_t)1 * CB + b) * CH + h) * CN + i];
    float il = 1.f / l;
    f16x4 Uh[4][2];
    #pragma unroll
    for (int r = 0; r < 4; ++r)
        #pragma unroll
        for (int eh = 0; eh < 2; ++eh) {
            Uh[r][eh][0] = (_Float16)(U[r][eh][0] * il);
            Uh[r][eh][1] = (_Float16)(U[r][eh][1] * il);
            Uh[r][eh][2] = (_Float16)(U[r][eh][2] * il);
            Uh[r][eh][3] = (_Float16)(U[r][eh][3] * il);
        }
    float rsv = rowsum[(size_t)b * CN + i];
    bool gate = rsv > 1e-6f;
    const float is2 = 0.70710678118654752f;
    #pragma unroll
    for (int eo = 0; eo < 2; ++eo) {
        f32x4 acc = {0.f, 0.f, 0.f, 0.f};
        #pragma unroll
        for (int r = 0; r < 4; ++r)
            #pragma unroll
            for (int ep = 0; ep < 2; ++ep) {
                f16x4 mt = *(const f16x4*)(MT + ((size_t)(r * 8 + h) * 32 + eo * 16 + col) * 32
                                               + ep * 16 + quad * 4);
                acc = __builtin_amdgcn_mfma_f32_16x16x16f16(mt, Uh[r][ep], acc, 0, 0, 0);
            }
        u16x4 hv, lv;
        #pragma unroll
        for (int k = 0; k < 4; ++k) {
            float x = gate ? acc[k] : 0.f;
            float g = 0.5f * x * (1.f + erff(x * is2));
            unsigned short hb = f2bf(g);
            hv[k] = hb; lv[k] = f2bf(g - bf2f(hb));
        }
        size_t off = ((size_t)b * CN + i) * COUT + h * CDK + eo * 16 + quad * 4;
        *(u16x4*)(Gh + off) = hv;
        *(u16x4*)(Gl + off) = lv;
    }
}

// ---------------------------------------------------------------------------
// gated residual + layernorm + soft-type mix; one wave per (b,i) row.
__global__ __launch_bounds__(256) void final_ln2(
    const float* __restrict__ trans, const float* __restrict__ x,
    const float* __restrict__ types, const float* __restrict__ skip,
    const float* __restrict__ gamma, const float* __restrict__ beta,
    float* __restrict__ out)
{
    int wave = threadIdx.x >> 6, lane = threadIdx.x & 63;
    int bi = blockIdx.x * 4 + wave;
    int b = bi >> 10, i = bi & 1023;
    f32x4 xo = *(const f32x4*)(x + (size_t)bi * COUT + lane * 4);
    f32x4 accum = {0.f, 0.f, 0.f, 0.f};
    const float* tp = types + (size_t)bi * CT;
    #pragma unroll 1
    for (int t = 0; t < CT; ++t) {
        float al = 1.f / (1.f + __expf(-skip[t]));
        f32x4 tr = *(const f32x4*)(trans + (((size_t)b * CT + t) * CN + i) * COUT + lane * 4);
        f32x4 res;
        float s = 0.f;
        #pragma unroll
        for (int k = 0; k < 4; ++k) { res[k] = tr[k] * al + xo[k] * (1.f - al); s += res[k]; }
        #pragma unroll
        for (int mk = 1; mk < 64; mk <<= 1) s += __shfl_xor(s, mk);
        float mu = s * (1.f / COUT);
        f32x4 dc; float s2 = 0.f;
        #pragma unroll
        for (int k = 0; k < 4; ++k) { dc[k] = res[k] - mu; s2 += dc[k] * dc[k]; }
        #pragma unroll
        for (int mk = 1; mk < 64; mk <<= 1) s2 += __shfl_xor(s2, mk);
        float inv = rsqrtf(s2 * (1.f / COUT) + 1e-5f);
        f32x4 g = *(const f32x4*)(gamma + (size_t)t * COUT + lane * 4);
        f32x4 be = *(const f32x4*)(beta + (size_t)t * COUT + lane * 4);
        float ty = tp[t];
        #pragma unroll
        for (int k = 0; k < 4; ++k) accum[k] += ty * (dc[k] * inv * g[k] + be[k]);
    }
    *(f32x4*)(out + (size_t)bi * COUT + lane * 4) = accum;
}

// ---------------------------------------------------------------------------
extern "C" void kernel_launch(void* const* d_in, const int* in_sizes, int n_in,
                              void* d_out, int out_size, void* d_ws, size_t ws_size,
                              hipStream_t stream)
{
    (void)in_sizes; (void)n_in; (void)out_size; (void)ws_size;
    const float* nf      = (const float*)d_in[0];
    const float* types   = (const float*)d_in[1];
    const float* adj     = (const float*)d_in[2];
    const float* erel    = (const float*)d_in[3];
    const float* Wq      = (const float*)d_in[4];
    const float* bq      = (const float*)d_in[5];
    const float* Wk      = (const float*)d_in[6];
    const float* bk      = (const float*)d_in[7];
    const float* Wv      = (const float*)d_in[8];
    const float* bv      = (const float*)d_in[9];
    const float* Wa      = (const float*)d_in[10];
    const float* ba      = (const float*)d_in[11];
    const float* rel_pri = (const float*)d_in[12];
    const float* rel_att = (const float*)d_in[13];
    const float* rel_msg = (const float*)d_in[14];
    const float* skip    = (const float*)d_in[15];
    const float* gamma   = (const float*)d_in[16];
    const float* beta    = (const float*)d_in[17];
    float* out = (float*)d_out;

    float* ws = (float*)d_ws;
    size_t o = 0;
    float* pool0 = ws + o; o += 3 * (size_t)CB * CT * CN * COUT;   // 9.44M f32
    float* Qt  = pool0;
    float* Ktb = pool0 + (size_t)CB * CT * CN * COUT;
    float* Vtb = pool0 + 2 * (size_t)CB * CT * CN * COUT;
    float* Qbar = ws + o; o += (size_t)CB * CN * COUT;
    float* rsb  = ws + o; o += (size_t)CB * CN;
    float* lbufp = ws + o; o += 2 * (size_t)CB * CH * CN;
    unsigned short* Qrhi = (unsigned short*)(ws + o); o += (size_t)CB * CR * CN * COUT / 2;
    unsigned short* Qrlo = (unsigned short*)(ws + o); o += (size_t)CB * CR * CN * COUT / 2;
    unsigned short* Kbh  = (unsigned short*)(ws + o); o += (size_t)CB * CH * CN * CDK / 2;
    unsigned short* Kbl  = (unsigned short*)(ws + o); o += (size_t)CB * CH * CN * CDK / 2;
    unsigned short* Kty  = (unsigned short*)(ws + o); o += (size_t)CB * CT * CH * CN * CDK / 2;
    _Float16* VTb = (_Float16*)(ws + o);              o += (size_t)CB * CT * CH * CDK * CN / 2;
    _Float16* MTb = (_Float16*)(ws + o);              o += (size_t)CR * CH * CDK * CDK / 2;
    unsigned short* Xh = (unsigned short*)(ws + o);   o += (size_t)CB * CN * COUT / 2;
    unsigned short* Xl = (unsigned short*)(ws + o);   o += (size_t)CB * CN * COUT / 2;
    unsigned short* Gh = (unsigned short*)(ws + o);   o += (size_t)CB * CN * COUT / 2;
    unsigned short* Gl = (unsigned short*)(ws + o);   o += (size_t)CB * CN * COUT / 2;
    unsigned short* WTh = (unsigned short*)(ws + o);  o += (size_t)12 * COUT * COUT / 2;
    unsigned short* WTl = (unsigned short*)(ws + o);  o += (size_t)12 * COUT * COUT / 2;
    float* coefT = ws + o; o += (size_t)CB * CN * CN * CR;   // 16.8M f32
    // overlays on pool0 (stream-ordered reuse): Upart written by attn4, dead
    // after merge_gelu; transb written by gemm(1) strictly after merge_gelu.
    float* Upart  = pool0;
    float* transb = pool0 + 3 * (size_t)CB * CN * COUT;

    prep0<<<5936, 256, 0, stream>>>(nf, Xh, Xl, Wq, Wk, Wv, Wa, WTh, WTl,
                                    rel_msg, MTb, rsb, adj, erel, coefT);
    mfma_gemm<<<dim3(8, 2, CB * 9), 256, 0, stream>>>(0, Xh, Xl, WTh, WTl,
                                                      bq, bk, bv, ba, Qt, Ktb, Vtb);
    mix_qbar<<<CB * CN * COUT / 4 / 256, 256, 0, stream>>>(Qt, types, Qbar);
    qr3_kernel<<<dim3(CN / 8, CR * CH, CB), 256, 0, stream>>>(Qbar, rel_att, rel_pri, Qrhi, Qrlo);
    prep_kv<<<2048, 256, 0, stream>>>(Ktb, Vtb, types, Kbh, Kbl, Kty, VTb);
    attn4_kernel<<<dim3(16, CH, CB * 2), 256, 0, stream>>>(Qrhi, Qrlo, Kbh, Kbl, Kty, VTb, coefT,
                                                           Upart, lbufp, rsb);
    merge_gelu<<<dim3(16, CH, CB), 256, 0, stream>>>(Upart, lbufp, MTb, rsb, Gh, Gl);
    mfma_gemm<<<dim3(8, 2, CB * CT), 256, 0, stream>>>(1, Gh, Gl, WTh, WTl,
                                                       bq, bk, bv, ba, transb, transb, transb);
    final_ln2<<<CB * CN / 4, 256, 0, stream>>>(transb, nf, types, skip, gamma, beta, out);
}